// Round 1
// baseline (620.975 us; speedup 1.0000x reference)
//
#include <hip/hip_runtime.h>
#include <hip/hip_bf16.h>
#include <hip/hip_cooperative_groups.h>

namespace cg = cooperative_groups;

#define N_NODES 10000
#define N_EDGES 640000
#define F_IN 128
#define H1 64
#define H2 32
#define N_CLASSES 16

#define GRID_B 512      // persistent blocks (2/CU guaranteed resident)
#define NB 256          // radix buckets
#define NPB 40          // nodes per bucket (256*40 = 10240 >= 10000)
#define STAGE_C 16      // per-bucket LDS staging cap (mean ~4.9/blk, spill path below)
#define SLOT 3072       // per-bucket partBuf capacity (mean 2500, +11 sigma)
#define IDX_CAP 4096    // per-block LDS index staging capacity
#define N_I4 (N_EDGES / 4)
#define I4PB 313        // ceil(160000/512) int4-chunks per block
#define GEMM_TILES 625  // 10000/16
#define G1_TILES 1250   // 10000/8
#define G2_TILES 625    // 10000/16

typedef unsigned short ushortT;

__device__ __forceinline__ float bf_lo(unsigned u) {
    u <<= 16; float f; __builtin_memcpy(&f, &u, 4); return f;
}
__device__ __forceinline__ float bf_hi(unsigned u) {
    u &= 0xffff0000u; float f; __builtin_memcpy(&f, &u, 4); return f;
}
__device__ __forceinline__ unsigned bf_pack(float a, float b) {
    __hip_bfloat16 ha = __float2bfloat16(a), hb = __float2bfloat16(b);
    unsigned short ua, ub;
    __builtin_memcpy(&ua, &ha, 2); __builtin_memcpy(&ub, &hb, 2);
    return (unsigned)ua | ((unsigned)ub << 16);
}

// Single fused cooperative kernel. Phases separated by grid.sync():
//   P0 init -> P1 edge-partition + GEMM1 -> P2 bucket sort + dinv scale
//   -> P3 gather1 + GEMM2 -> P4 gather2 + mean + FC
__global__ void __launch_bounds__(256, 2) k_fused(
        const int* __restrict__ srcI, const int* __restrict__ dstI,
        const float* __restrict__ x, const float* __restrict__ W1,
        const float* __restrict__ b1, const float* __restrict__ W2,
        const float* __restrict__ b2, const float* __restrict__ Wfc,
        const float* __restrict__ bfc, float* __restrict__ out,
        int* __restrict__ bucketCursor, int* __restrict__ workCtr,
        float* __restrict__ dinv, int* __restrict__ rowStart,
        ushortT* __restrict__ srcU, int* __restrict__ partBuf,
        __hip_bfloat16* __restrict__ h1b, __hip_bfloat16* __restrict__ h2b) {
    cg::grid_group grid = cg::this_grid();
    __shared__ __align__(16) char pool[40960];
    const int t = threadIdx.x;
    const int g = blockIdx.x;

    // ---------------- P0: init (block 0 only) ----------------
    if (g == 0) {
        if (t < NB) bucketCursor[t] = 0;
        if (t < 2) workCtr[t] = 0;
        if (t == 0) rowStart[N_NODES] = N_EDGES;
        if (t < N_CLASSES) out[t] = bfc[t];
    }
    __threadfence();
    grid.sync();
    __threadfence();

    // ---------------- P1a: edge partition ----------------
    {
        int* cnt   = (int*)pool;            // 256 ints
        int* gbase = (int*)(pool + 1024);   // 256 ints
        int* stage = (int*)(pool + 2048);   // 256*16 ints = 16 KB
        if (t < NB) cnt[t] = 0;
        __syncthreads();
        const int4* src4 = (const int4*)srcI;
        const int4* dst4 = (const int4*)dstI;
        for (int ii = t; ii < I4PB; ii += 256) {
            int i4 = g * I4PB + ii;
            if (i4 < N_I4) {
                int4 s = src4[i4];
                int4 d = dst4[i4];
                int b, l, p, val;
                b = d.x / NPB; l = d.x - b * NPB; val = s.x | (l << 14);
                p = atomicAdd(&cnt[b], 1);
                if (p < STAGE_C) stage[(b << 4) + p] = val;
                else partBuf[b * SLOT + atomicAdd(&bucketCursor[b], 1)] = val;
                b = d.y / NPB; l = d.y - b * NPB; val = s.y | (l << 14);
                p = atomicAdd(&cnt[b], 1);
                if (p < STAGE_C) stage[(b << 4) + p] = val;
                else partBuf[b * SLOT + atomicAdd(&bucketCursor[b], 1)] = val;
                b = d.z / NPB; l = d.z - b * NPB; val = s.z | (l << 14);
                p = atomicAdd(&cnt[b], 1);
                if (p < STAGE_C) stage[(b << 4) + p] = val;
                else partBuf[b * SLOT + atomicAdd(&bucketCursor[b], 1)] = val;
                b = d.w / NPB; l = d.w - b * NPB; val = s.w | (l << 14);
                p = atomicAdd(&cnt[b], 1);
                if (p < STAGE_C) stage[(b << 4) + p] = val;
                else partBuf[b * SLOT + atomicAdd(&bucketCursor[b], 1)] = val;
            }
        }
        __syncthreads();
        if (t < NB) {
            int c = cnt[t]; if (c > STAGE_C) c = STAGE_C;
            gbase[t] = atomicAdd(&bucketCursor[t], c);
            cnt[t] = c;
        }
        __syncthreads();
#pragma unroll
        for (int rep = 0; rep < (NB * STAGE_C) / 256; ++rep) {
            int i = rep * 256 + t;
            int b = i >> 4, k = i & 15;
            if (k < cnt[b]) partBuf[b * SLOT + gbase[b] + k] = stage[i];
        }
        __syncthreads();   // release pool for GEMM1
    }

    // ---------------- P1b: GEMM1 h1b = bf16(x @ W1), unscaled ----------------
    {
        float* w1s = (float*)pool;            // [128][64] = 32 KB
        float* xs  = (float*)(pool + 32768);  // [16][128] = 8 KB
        const float4* W14 = (const float4*)W1;
        float4* w1s4 = (float4*)w1s;
#pragma unroll
        for (int i = 0; i < 8; ++i) w1s4[i * 256 + t] = W14[i * 256 + t];
        for (int tile = g; tile < GEMM_TILES; tile += GRID_B) {
            int node0 = tile * 16;
            const float4* x4 = (const float4*)(x + node0 * F_IN);
            float4* xs4 = (float4*)xs;
#pragma unroll
            for (int i = 0; i < 2; ++i) xs4[i * 256 + t] = x4[i * 256 + t];
            __syncthreads();
            int j = t & 63, q = t >> 6, r0 = q * 4;
            float a0 = 0.f, a1 = 0.f, a2 = 0.f, a3 = 0.f;
#pragma unroll 4
            for (int k = 0; k < F_IN; ++k) {
                float w = w1s[k * H1 + j];
                a0 += xs[(r0 + 0) * F_IN + k] * w;
                a1 += xs[(r0 + 1) * F_IN + k] * w;
                a2 += xs[(r0 + 2) * F_IN + k] * w;
                a3 += xs[(r0 + 3) * F_IN + k] * w;
            }
            int v0 = node0 + r0;
            h1b[(v0 + 0) * H1 + j] = __float2bfloat16(a0);
            h1b[(v0 + 1) * H1 + j] = __float2bfloat16(a1);
            h1b[(v0 + 2) * H1 + j] = __float2bfloat16(a2);
            h1b[(v0 + 3) * H1 + j] = __float2bfloat16(a3);
            __syncthreads();
        }
    }
    __threadfence();
    grid.sync();
    __threadfence();

    // ---------------- P2: per-bucket counting sort + dinv + h1 scale ----------------
    if (g < NB) {
        int* sc    = (int*)pool;            // 256 ints
        int* ldeg  = (int*)(pool + 1024);   // 40
        int* lpre  = (int*)(pool + 1344);   // 40
        int* cur   = (int*)(pool + 1664);   // 40
        float* sdv = (float*)(pool + 1984); // 40
        sc[t] = bucketCursor[t];            // t < 256 == NB
        __syncthreads();
        for (int off = 1; off < NB; off <<= 1) {
            int vv = (t >= off) ? sc[t - off] : 0;
            __syncthreads();
            sc[t] += vv;
            __syncthreads();
        }
        int cnt = bucketCursor[g];
        int base = sc[g] - cnt;             // exclusive prefix
        int nodeBase = g * NPB;
        int nNodes = N_NODES - nodeBase;
        if (nNodes > 0) {
            if (nNodes > NPB) nNodes = NPB;
            if (t < NPB) ldeg[t] = 0;
            __syncthreads();
            for (int i = t; i < cnt; i += 256)
                atomicAdd(&ldeg[partBuf[g * SLOT + i] >> 14], 1);
            __syncthreads();
            if (t == 0) {
                int run = 0;
                for (int i = 0; i < nNodes; ++i) { lpre[i] = run; run += ldeg[i]; }
            }
            __syncthreads();
            if (t < nNodes) {
                int v = nodeBase + t;
                rowStart[v] = base + lpre[t];
                cur[t] = lpre[t];
                float dv_ = rsqrtf((float)ldeg[t] + 1.0f);
                dinv[v] = dv_;
                sdv[t] = dv_;
            }
            __syncthreads();
            for (int i = t; i < cnt; i += 256) {
                int p = partBuf[g * SLOT + i];
                int pos = atomicAdd(&cur[p >> 14], 1);
                srcU[base + pos] = (ushortT)(p & 16383);
            }
            unsigned* h1u = (unsigned*)h1b;
            for (int i = t; i < nNodes * 32; i += 256) {
                int ln = i >> 5, pp = i & 31;
                int v = nodeBase + ln;
                unsigned u = h1u[v * 32 + pp];
                float d = sdv[ln];
                h1u[v * 32 + pp] = bf_pack(bf_lo(u) * d, bf_hi(u) * d);
            }
        }
    }
    __threadfence();
    grid.sync();
    __threadfence();

    // ---------------- P3: gather layer1 + ReLU + GEMM2 ----------------
    {
        float* h1s    = (float*)pool;               // [8][64] = 2 KB
        ushortT* idxs = (ushortT*)(pool + 2048);    // 8 KB
        int* sW       = (int*)(pool + 10240);       // [0]=rs0 [1]=re [2]=tile
        float* w2s    = (float*)(pool + 10256);     // [64][32] = 8 KB
        const float4* W24 = (const float4*)W2;
        float4* w2s4 = (float4*)w2s;
#pragma unroll
        for (int i = 0; i < 2; ++i) w2s4[i * 256 + t] = W24[i * 256 + t];
        const unsigned* h1u = (const unsigned*)h1b;
        int n = t >> 5, fp = t & 31;
        while (true) {
            if (t == 0) sW[2] = atomicAdd(&workCtr[0], 1);
            __syncthreads();
            int tile = sW[2];
            if (tile >= G1_TILES) break;
            if (t == 0) { sW[0] = rowStart[tile * 8]; sW[1] = rowStart[tile * 8 + 8]; }
            __syncthreads();
            int rs0 = sW[0], cnt0 = sW[1] - rs0;
            int v = tile * 8 + n;
            bool useLds = (cnt0 <= IDX_CAP);
            if (useLds) for (int i = t; i < cnt0; i += 256) idxs[i] = srcU[rs0 + i];
            float dv_ = dinv[v];
            int rs = rowStart[v], re = rowStart[v + 1];
            unsigned su = h1u[v * 32 + fp];
            float fx = bf_lo(su), fy = bf_hi(su);
            float x0 = 0.f, y0 = 0.f, x1 = 0.f, y1 = 0.f;
            float x2 = 0.f, y2 = 0.f, x3 = 0.f, y3 = 0.f;
            __syncthreads();
            if (useLds) {
                int le = rs - rs0, lend = re - rs0;
                for (; le + 4 <= lend; le += 4) {
                    int i0 = idxs[le],     i1 = idxs[le + 1];
                    int i2 = idxs[le + 2], i3 = idxs[le + 3];
                    unsigned u0 = h1u[i0 * 32 + fp];
                    unsigned u1 = h1u[i1 * 32 + fp];
                    unsigned u2 = h1u[i2 * 32 + fp];
                    unsigned u3 = h1u[i3 * 32 + fp];
                    x0 += bf_lo(u0); y0 += bf_hi(u0);
                    x1 += bf_lo(u1); y1 += bf_hi(u1);
                    x2 += bf_lo(u2); y2 += bf_hi(u2);
                    x3 += bf_lo(u3); y3 += bf_hi(u3);
                }
                for (; le < lend; ++le) {
                    unsigned u = h1u[idxs[le] * 32 + fp];
                    fx += bf_lo(u); fy += bf_hi(u);
                }
            } else {
                for (int e = rs; e < re; ++e) {
                    unsigned u = h1u[(int)srcU[e] * 32 + fp];
                    fx += bf_lo(u); fy += bf_hi(u);
                }
            }
            fx += (x0 + x1) + (x2 + x3);
            fy += (y0 + y1) + (y2 + y3);
            ((float2*)(h1s + n * H1))[fp] =
                make_float2(fmaxf(dv_ * fx + b1[fp * 2], 0.f),
                            fmaxf(dv_ * fy + b1[fp * 2 + 1], 0.f));
            __syncthreads();
            float acc = 0.f;
#pragma unroll
            for (int kk = 0; kk < H1; ++kk)
                acc += h1s[n * H1 + kk] * w2s[kk * H2 + fp];
            h2b[v * H2 + fp] = __float2bfloat16(acc * dv_);  // pre-scaled
            __syncthreads();
        }
    }
    __threadfence();
    grid.sync();
    __threadfence();

    // ---------------- P4: gather layer2 + ReLU + mean + FC ----------------
    {
        float* red    = (float*)pool;               // [16][32] = 2 KB
        ushortT* idxs = (ushortT*)(pool + 2048);    // 8 KB
        int* sW       = (int*)(pool + 10240);
        float* gs     = (float*)(pool + 10256);     // 32 floats
        const unsigned* h2u = (const unsigned*)h2b;
        int n = t >> 4, fp = t & 15;
        while (true) {
            if (t == 0) sW[2] = atomicAdd(&workCtr[1], 1);
            __syncthreads();
            int tile = sW[2];
            if (tile >= G2_TILES) break;
            if (t == 0) { sW[0] = rowStart[tile * 16]; sW[1] = rowStart[tile * 16 + 16]; }
            __syncthreads();
            int rs0 = sW[0], cnt0 = sW[1] - rs0;
            int v = tile * 16 + n;
            bool useLds = (cnt0 <= IDX_CAP);
            if (useLds) for (int i = t; i < cnt0; i += 256) idxs[i] = srcU[rs0 + i];
            float dv_ = dinv[v];
            int rs = rowStart[v], re = rowStart[v + 1];
            unsigned su = h2u[v * 16 + fp];
            float fx = bf_lo(su), fy = bf_hi(su);
            float x0 = 0.f, y0 = 0.f, x1 = 0.f, y1 = 0.f;
            float x2 = 0.f, y2 = 0.f, x3 = 0.f, y3 = 0.f;
            __syncthreads();
            if (useLds) {
                int le = rs - rs0, lend = re - rs0;
                for (; le + 4 <= lend; le += 4) {
                    int i0 = idxs[le],     i1 = idxs[le + 1];
                    int i2 = idxs[le + 2], i3 = idxs[le + 3];
                    unsigned u0 = h2u[i0 * 16 + fp];
                    unsigned u1 = h2u[i1 * 16 + fp];
                    unsigned u2 = h2u[i2 * 16 + fp];
                    unsigned u3 = h2u[i3 * 16 + fp];
                    x0 += bf_lo(u0); y0 += bf_hi(u0);
                    x1 += bf_lo(u1); y1 += bf_hi(u1);
                    x2 += bf_lo(u2); y2 += bf_hi(u2);
                    x3 += bf_lo(u3); y3 += bf_hi(u3);
                }
                for (; le < lend; ++le) {
                    unsigned u = h2u[idxs[le] * 16 + fp];
                    fx += bf_lo(u); fy += bf_hi(u);
                }
            } else {
                for (int e = rs; e < re; ++e) {
                    unsigned u = h2u[(int)srcU[e] * 16 + fp];
                    fx += bf_lo(u); fy += bf_hi(u);
                }
            }
            fx += (x0 + x1) + (x2 + x3);
            fy += (y0 + y1) + (y2 + y3);
            ((float2*)(red + n * H2))[fp] =
                make_float2(fmaxf(dv_ * fx + b2[fp * 2], 0.f),
                            fmaxf(dv_ * fy + b2[fp * 2 + 1], 0.f));
            __syncthreads();
            if (t < H2) {
                float s = 0.f;
#pragma unroll
                for (int r = 0; r < 16; ++r) s += red[r * H2 + t];
                gs[t] = s;
            }
            __syncthreads();
            if (t < N_CLASSES) {
                float acc = 0.f;
#pragma unroll
                for (int jj = 0; jj < H2; ++jj)
                    acc += gs[jj] * Wfc[jj * N_CLASSES + t];
                atomicAdd(&out[t], acc * (1.0f / (float)N_NODES));
            }
            __syncthreads();
        }
    }
}

extern "C" void kernel_launch(void* const* d_in, const int* in_sizes, int n_in,
                              void* d_out, int out_size, void* d_ws, size_t ws_size,
                              hipStream_t stream) {
    const float* x   = (const float*)d_in[0];
    const float* W1  = (const float*)d_in[1];
    const float* b1  = (const float*)d_in[2];
    const float* W2  = (const float*)d_in[3];
    const float* b2  = (const float*)d_in[4];
    const float* Wfc = (const float*)d_in[5];
    const float* bfc = (const float*)d_in[6];
    const int* edge  = (const int*)d_in[7];
    const int* srcI = edge;              // edge_index[0]
    const int* dstI = edge + N_EDGES;    // edge_index[1]
    float* out = (float*)d_out;

    // workspace layout; all init (cursor/workCtr/out-seed) done in-kernel P0.
    char* ws = (char*)d_ws;
    int*     bucketCursor = (int*)    (ws + 0);        // 256 ints
    float*   dinv         = (float*)  (ws + 1024);     // 10000 f -> 41024
    int*     workCtr      = (int*)    (ws + 41472);    // 2 ints
    int*     rowStart     = (int*)    (ws + 41984);    // 10001 ints -> 81988
    ushortT* srcU         = (ushortT*)(ws + 82944);    // 640000 u16 -> 1362944
    int*     partBuf      = (int*)    (ws + 1363968);  // 256*3072 ints -> 4509696
    __hip_bfloat16* h1b   = (__hip_bfloat16*)(ws + 4509696);  // 640000 bf16 -> 5789696
    __hip_bfloat16* h2b   = (__hip_bfloat16*)(ws + 5789696);  // 320000 bf16 -> 6429696

    void* kargs[] = {
        (void*)&srcI, (void*)&dstI, (void*)&x, (void*)&W1, (void*)&b1,
        (void*)&W2, (void*)&b2, (void*)&Wfc, (void*)&bfc, (void*)&out,
        (void*)&bucketCursor, (void*)&workCtr, (void*)&dinv, (void*)&rowStart,
        (void*)&srcU, (void*)&partBuf, (void*)&h1b, (void*)&h2b
    };
    hipLaunchCooperativeKernel((const void*)k_fused, dim3(GRID_B), dim3(256),
                               kargs, 0, stream);
}

// Round 2
// 184.551 us; speedup vs baseline: 3.3648x; 3.3648x over previous
//
#include <hip/hip_runtime.h>
#include <hip/hip_bf16.h>

#define N_NODES 10000
#define N_EDGES 640000
#define F_IN 128
#define H1 64
#define H2 32
#define N_CLASSES 16

#define NB 256          // radix buckets
#define NPB 40          // nodes per bucket (256*40 = 10240 >= 10000; buckets 250+ empty)
#define STAGE_C 32      // per-(block,bucket) staging/region capacity (mean 4, ~15 sigma)
#define PART_BLOCKS 625 // 625*256 int4 = 160000 exactly -> 1024 edges/block
#define SLOT_B (PART_BLOCKS * STAGE_C)   // 20000 slots per bucket region
#define IDX_CAP 4096    // per-block LDS index staging capacity
#define GEMM_TILES 625  // 10000/16

typedef unsigned short ushortT;

__device__ __forceinline__ float bf_lo(unsigned u) {
    u <<= 16; float f; __builtin_memcpy(&f, &u, 4); return f;
}
__device__ __forceinline__ float bf_hi(unsigned u) {
    u &= 0xffff0000u; float f; __builtin_memcpy(&f, &u, 4); return f;
}
__device__ __forceinline__ unsigned bf_pack(float a, float b) {
    __hip_bfloat16 ha = __float2bfloat16(a), hb = __float2bfloat16(b);
    unsigned short ua, ub;
    __builtin_memcpy(&ua, &ha, 2); __builtin_memcpy(&ub, &hb, 2);
    return (unsigned)ua | ((unsigned)ub << 16);
}

// ---------- dispatch 1: edge partition (blocks 0..624) + GEMM1 (625..1249) ----------
// part: pack src(14b) | local_dst(6b)<<14 into 256 dst-range buckets, each block
//       writing its own fixed region partBuf[b*SLOT_B + g*32 + k]. Counts go to
//       gcnt[g*NB+b] unconditionally -> NO zero-init, NO global atomics, NO memset.
// gemm: h1b = bf16(x @ W1), UNSCALED — dinv applied in-place by k_bsort.
__global__ void __launch_bounds__(256) k_part_gemm1(const int* __restrict__ src,
                                                    const int* __restrict__ dst,
                                                    int* __restrict__ gcnt,
                                                    int* __restrict__ partBuf,
                                                    const float* __restrict__ x,
                                                    const float* __restrict__ W1,
                                                    __hip_bfloat16* __restrict__ h1b,
                                                    const float* __restrict__ bfc,
                                                    float* __restrict__ out) {
    __shared__ __align__(16) char pool[40960];  // union: part 33KB / gemm 40KB
    int t = threadIdx.x;
    if (blockIdx.x < PART_BLOCKS) {
        int g = blockIdx.x;
        int* cnt   = (int*)pool;           // 256 ints
        int* stage = (int*)(pool + 1024);  // 256*32 ints = 32 KB
        if (t < NB) cnt[t] = 0;
        __syncthreads();
        const int4* src4 = (const int4*)src;
        const int4* dst4 = (const int4*)dst;
        int i4 = g * 256 + t;              // always < 160000
        int4 s = src4[i4];
        int4 d = dst4[i4];
        int b, l, p;
        b = d.x / NPB; l = d.x - b * NPB; p = atomicAdd(&cnt[b], 1);
        if (p < STAGE_C) stage[(b << 5) + p] = s.x | (l << 14);
        b = d.y / NPB; l = d.y - b * NPB; p = atomicAdd(&cnt[b], 1);
        if (p < STAGE_C) stage[(b << 5) + p] = s.y | (l << 14);
        b = d.z / NPB; l = d.z - b * NPB; p = atomicAdd(&cnt[b], 1);
        if (p < STAGE_C) stage[(b << 5) + p] = s.z | (l << 14);
        b = d.w / NPB; l = d.w - b * NPB; p = atomicAdd(&cnt[b], 1);
        if (p < STAGE_C) stage[(b << 5) + p] = s.w | (l << 14);
        __syncthreads();
        if (t < NB) {
            int c = cnt[t]; if (c > STAGE_C) c = STAGE_C;  // memory-safety clamp
            cnt[t] = c;
            gcnt[g * NB + t] = c;          // coalesced, unconditional
        }
        __syncthreads();
#pragma unroll
        for (int rep = 0; rep < (NB * STAGE_C) / 256; ++rep) {
            int i = rep * 256 + t;
            int bb = i >> 5, k = i & 31;
            if (k < cnt[bb]) partBuf[bb * SLOT_B + g * STAGE_C + k] = stage[i];
        }
    } else {
        int gb = blockIdx.x - PART_BLOCKS;   // 0..624
        float* w1s = (float*)pool;           // [128][64] = 32 KB
        float* xs  = (float*)(pool + 32768); // [16][128] = 8 KB
        int node0 = gb * 16;                 // 625*16 = 10000 exact
        const float4* W14 = (const float4*)W1;
        float4* w1s4 = (float4*)w1s;
#pragma unroll
        for (int i = 0; i < 8; ++i) w1s4[i * 256 + t] = W14[i * 256 + t];
        const float4* x4 = (const float4*)(x + (long)node0 * F_IN);
        float4* xs4 = (float4*)xs;
#pragma unroll
        for (int i = 0; i < 2; ++i) xs4[i * 256 + t] = x4[i * 256 + t];
        if (gb == 0 && t < N_CLASSES) out[t] = bfc[t];  // seed output with bias
        __syncthreads();
        int j = t & 63;
        int q = t >> 6;       // wave id 0..3
        int r0 = q * 4;
        float acc0 = 0.f, acc1 = 0.f, acc2 = 0.f, acc3 = 0.f;
#pragma unroll 4
        for (int k = 0; k < F_IN; ++k) {
            float w = w1s[k * H1 + j];
            acc0 += xs[(r0 + 0) * F_IN + k] * w;
            acc1 += xs[(r0 + 1) * F_IN + k] * w;
            acc2 += xs[(r0 + 2) * F_IN + k] * w;
            acc3 += xs[(r0 + 3) * F_IN + k] * w;
        }
        int v0 = node0 + r0;
        h1b[(v0 + 0) * H1 + j] = __float2bfloat16(acc0);
        h1b[(v0 + 1) * H1 + j] = __float2bfloat16(acc1);
        h1b[(v0 + 2) * H1 + j] = __float2bfloat16(acc2);
        h1b[(v0 + 3) * H1 + j] = __float2bfloat16(acc3);
    }
}

// ---------- dispatch 2: per-bucket counting sort + dinv + in-place h1 scale ----------
// 256 blocks x 512. Block b: totals from gcnt (redundant per-block), cross-bucket
// scan in LDS, local degree count, thread-0 prefix over 40, place srcU, scale h1.
__global__ void __launch_bounds__(512) k_bsort(const int* __restrict__ gcnt,
                                               const int* __restrict__ partBuf,
                                               ushortT* __restrict__ srcU,
                                               int* __restrict__ rowStart,
                                               float* __restrict__ dinv,
                                               __hip_bfloat16* __restrict__ h1b) {
    __shared__ int tot2[2][NB];   // 2 KB
    __shared__ int sc[NB];        // 1 KB (inclusive scan)
    __shared__ int tot[NB];       // 1 KB
    __shared__ int scnt[PART_BLOCKS]; // 2.5 KB: this bucket's per-part-block counts
    __shared__ int ldeg[NPB];
    __shared__ int lpre[NPB];
    __shared__ int cur[NPB];
    __shared__ float sdv[NPB];
    int t = threadIdx.x;
    int b = blockIdx.x;
    int nodeBase = b * NPB;
    if (nodeBase >= N_NODES) return;   // buckets 250..255 are empty
    if (b == 0 && t == 0) rowStart[N_NODES] = N_EDGES;
    // bucket totals: two half-sums over part-blocks, then combine
    {
        int tt = t & 255, hf = t >> 8;
        int lo = hf * 313, hi = hf ? PART_BLOCKS : 313;
        int s = 0;
        for (int pb = lo; pb < hi; ++pb) s += gcnt[pb * NB + tt];
        tot2[hf][tt] = s;
    }
    __syncthreads();
    if (t < NB) { int s = tot2[0][t] + tot2[1][t]; tot[t] = s; sc[t] = s; }
    __syncthreads();
    for (int off = 1; off < NB; off <<= 1) {
        int v = (t >= off && t < NB) ? sc[t - off] : 0;
        __syncthreads();
        if (t < NB) sc[t] += v;
        __syncthreads();
    }
    int cnt = tot[b];
    int base = sc[b] - cnt;            // exclusive prefix
    // stage this bucket's per-part-block counts
    for (int pb = t; pb < PART_BLOCKS; pb += 512) scnt[pb] = gcnt[pb * NB + b];
    int nNodes = N_NODES - nodeBase;
    if (nNodes > NPB) nNodes = NPB;
    if (t < NPB) ldeg[t] = 0;
    __syncthreads();
    // count local degrees over fixed-region slots
    const int* myBuf = partBuf + b * SLOT_B;
    for (int idx = t; idx < SLOT_B; idx += 512) {
        if ((idx & 31) < scnt[idx >> 5])
            atomicAdd(&ldeg[myBuf[idx] >> 14], 1);
    }
    __syncthreads();
    if (t == 0) {
        int run = 0;
        for (int i = 0; i < nNodes; ++i) { lpre[i] = run; run += ldeg[i]; }
    }
    __syncthreads();
    if (t < nNodes) {
        int v = nodeBase + t;
        rowStart[v] = base + lpre[t];
        cur[t] = lpre[t];
        float dv_ = rsqrtf((float)ldeg[t] + 1.0f);
        dinv[v] = dv_;
        sdv[t] = dv_;
    }
    __syncthreads();
    // place
    for (int idx = t; idx < SLOT_B; idx += 512) {
        if ((idx & 31) < scnt[idx >> 5]) {
            int p = myBuf[idx];
            int pos = atomicAdd(&cur[p >> 14], 1);
            srcU[base + pos] = (ushortT)(p & 16383);
        }
    }
    // scale this bucket's h1 rows by dinv, in place (bf16 pairs as u32)
    unsigned* h1u = (unsigned*)h1b;
    for (int i = t; i < nNodes * 32; i += 512) {
        int ln = i >> 5, pp = i & 31;
        int v = nodeBase + ln;
        unsigned u = h1u[v * 32 + pp];
        float d = sdv[ln];
        h1u[v * 32 + pp] = bf_pack(bf_lo(u) * d, bf_hi(u) * d);
    }
}

// ---------- dispatch 3: gather layer1 (CSR, bf16x2, LDS-staged u16 idx) + ReLU + GEMM2 ----------
// 1250 blocks x 256 threads = 8 nodes x 32 lanes; lane owns feature pair.
__global__ void __launch_bounds__(256) k_gather1_gemm2(const __hip_bfloat16* __restrict__ h1b,
                                const int* __restrict__ rowStart,
                                const ushortT* __restrict__ srcU,
                                const float* __restrict__ dinv,
                                const float* __restrict__ b1,
                                const float* __restrict__ W2,
                                __hip_bfloat16* __restrict__ h2b) {
    __shared__ float h1s[8][H1];       // 2 KB
    __shared__ ushortT idxs[IDX_CAP];  // 8 KB
    __shared__ int sRange[2];
    int t = threadIdx.x;
    int n  = t >> 5;        // node slot 0..7
    int fp = t & 31;        // feature pair
    int v = blockIdx.x * 8 + n;   // 1250*8 = 10000 exact
    if (t == 0) { sRange[0] = rowStart[blockIdx.x * 8]; sRange[1] = rowStart[blockIdx.x * 8 + 8]; }
    __syncthreads();
    int rs0 = sRange[0];
    int cnt0 = sRange[1] - rs0;
    bool useLds = (cnt0 <= IDX_CAP);
    if (useLds) for (int i = t; i < cnt0; i += 256) idxs[i] = srcU[rs0 + i];
    float dv_ = dinv[v];
    int rs = rowStart[v], re = rowStart[v + 1];
    const unsigned* h1u = (const unsigned*)h1b;
    unsigned su = h1u[v * 32 + fp];          // self-loop term
    float fx = bf_lo(su), fy = bf_hi(su);
    float x0 = 0.f, y0 = 0.f, x1 = 0.f, y1 = 0.f;
    float x2 = 0.f, y2 = 0.f, x3 = 0.f, y3 = 0.f;
    __syncthreads();
    if (useLds) {
        int le = rs - rs0, lend = re - rs0;
        for (; le + 4 <= lend; le += 4) {
            int i0 = idxs[le],     i1 = idxs[le + 1];
            int i2 = idxs[le + 2], i3 = idxs[le + 3];
            unsigned u0 = h1u[i0 * 32 + fp];
            unsigned u1 = h1u[i1 * 32 + fp];
            unsigned u2 = h1u[i2 * 32 + fp];
            unsigned u3 = h1u[i3 * 32 + fp];
            x0 += bf_lo(u0); y0 += bf_hi(u0);
            x1 += bf_lo(u1); y1 += bf_hi(u1);
            x2 += bf_lo(u2); y2 += bf_hi(u2);
            x3 += bf_lo(u3); y3 += bf_hi(u3);
        }
        for (; le < lend; ++le) {
            unsigned u = h1u[idxs[le] * 32 + fp];
            fx += bf_lo(u); fy += bf_hi(u);
        }
    } else {  // fallback: direct global reads (degree-skew safety, ~never taken)
        for (int e = rs; e < re; ++e) {
            unsigned u = h1u[(int)srcU[e] * 32 + fp];
            fx += bf_lo(u); fy += bf_hi(u);
        }
    }
    fx += (x0 + x1) + (x2 + x3);
    fy += (y0 + y1) + (y2 + y3);
    ((float2*)h1s[n])[fp] = make_float2(fmaxf(dv_ * fx + b1[fp * 2], 0.f),
                                        fmaxf(dv_ * fy + b1[fp * 2 + 1], 0.f));
    __syncthreads();
    // GEMM2: thread = (node n, output j=fp in [0,32))
    float acc = 0.f;
#pragma unroll
    for (int kk = 0; kk < H1; ++kk)
        acc += h1s[n][kk] * W2[kk * H2 + fp];
    h2b[v * H2 + fp] = __float2bfloat16(acc * dv_);  // pre-scaled
}

// ---------- dispatch 4: gather layer2 + ReLU + partial mean + partial FC -> out ----------
// 625 blocks x 256 threads = 16 nodes x 16 lanes. out pre-seeded with bfc;
// each block atomically adds its partial (mean @ Wfc) — linear, so exact.
__global__ void __launch_bounds__(256) k_gather2_out(const __hip_bfloat16* __restrict__ h2b,
                               const int* __restrict__ rowStart,
                               const ushortT* __restrict__ srcU,
                               const float* __restrict__ dinv,
                               const float* __restrict__ b2,
                               const float* __restrict__ Wfc,
                               float* __restrict__ out) {
    __shared__ float red[16][H2];      // 2 KB
    __shared__ ushortT idxs[IDX_CAP];  // 8 KB
    __shared__ int sRange[2];
    __shared__ float gs[H2];
    int t = threadIdx.x;
    int n  = t >> 4;        // node slot 0..15
    int fp = t & 15;        // feature pair of H2
    int v = blockIdx.x * 16 + n;   // 625*16 = 10000 exact
    if (t == 0) { sRange[0] = rowStart[blockIdx.x * 16]; sRange[1] = rowStart[blockIdx.x * 16 + 16]; }
    __syncthreads();
    int rs0 = sRange[0];
    int cnt0 = sRange[1] - rs0;
    bool useLds = (cnt0 <= IDX_CAP);
    if (useLds) for (int i = t; i < cnt0; i += 256) idxs[i] = srcU[rs0 + i];
    float dv_ = dinv[v];
    int rs = rowStart[v], re = rowStart[v + 1];
    const unsigned* h2u = (const unsigned*)h2b;
    unsigned su = h2u[v * 16 + fp];          // self-loop term
    float fx = bf_lo(su), fy = bf_hi(su);
    float x0 = 0.f, y0 = 0.f, x1 = 0.f, y1 = 0.f;
    float x2 = 0.f, y2 = 0.f, x3 = 0.f, y3 = 0.f;
    __syncthreads();
    if (useLds) {
        int le = rs - rs0, lend = re - rs0;
        for (; le + 4 <= lend; le += 4) {
            int i0 = idxs[le],     i1 = idxs[le + 1];
            int i2 = idxs[le + 2], i3 = idxs[le + 3];
            unsigned u0 = h2u[i0 * 16 + fp];
            unsigned u1 = h2u[i1 * 16 + fp];
            unsigned u2 = h2u[i2 * 16 + fp];
            unsigned u3 = h2u[i3 * 16 + fp];
            x0 += bf_lo(u0); y0 += bf_hi(u0);
            x1 += bf_lo(u1); y1 += bf_hi(u1);
            x2 += bf_lo(u2); y2 += bf_hi(u2);
            x3 += bf_lo(u3); y3 += bf_hi(u3);
        }
        for (; le < lend; ++le) {
            unsigned u = h2u[idxs[le] * 16 + fp];
            fx += bf_lo(u); fy += bf_hi(u);
        }
    } else {
        for (int e = rs; e < re; ++e) {
            unsigned u = h2u[(int)srcU[e] * 16 + fp];
            fx += bf_lo(u); fy += bf_hi(u);
        }
    }
    fx += (x0 + x1) + (x2 + x3);
    fy += (y0 + y1) + (y2 + y3);
    ((float2*)red[n])[fp] = make_float2(fmaxf(dv_ * fx + b2[fp * 2], 0.f),
                                        fmaxf(dv_ * fy + b2[fp * 2 + 1], 0.f));
    __syncthreads();
    if (t < H2) {
        float s = 0.f;
#pragma unroll
        for (int r = 0; r < 16; ++r) s += red[r][t];
        gs[t] = s;
    }
    __syncthreads();
    if (t < N_CLASSES) {
        float acc = 0.f;
#pragma unroll
        for (int j = 0; j < H2; ++j)
            acc += gs[j] * Wfc[j * N_CLASSES + t];
        atomicAdd(&out[t], acc * (1.0f / (float)N_NODES));
    }
}

extern "C" void kernel_launch(void* const* d_in, const int* in_sizes, int n_in,
                              void* d_out, int out_size, void* d_ws, size_t ws_size,
                              hipStream_t stream) {
    const float* x   = (const float*)d_in[0];
    const float* W1  = (const float*)d_in[1];
    const float* b1  = (const float*)d_in[2];
    const float* W2  = (const float*)d_in[3];
    const float* b2  = (const float*)d_in[4];
    const float* Wfc = (const float*)d_in[5];
    const float* bfc = (const float*)d_in[6];
    const int* edge  = (const int*)d_in[7];
    const int* srcI = edge;              // edge_index[0]
    const int* dstI = edge + N_EDGES;    // edge_index[1]
    float* out = (float*)d_out;

    // workspace layout (~24.5 MB); NO init required (gcnt written unconditionally).
    char* ws = (char*)d_ws;
    int*     gcnt     = (int*)    (ws + 0);          // 625*256 ints = 640000 B
    float*   dinv     = (float*)  (ws + 655360);     // 10000 f
    int*     rowStart = (int*)    (ws + 696320);     // 10001 ints
    ushortT* srcU     = (ushortT*)(ws + 737280);     // 640000 u16 -> ends 2017280
    int*     partBuf  = (int*)    (ws + 2097152);    // 256*20000 ints -> ends 22577152
    __hip_bfloat16* h1b = (__hip_bfloat16*)(ws + 22577152);  // 640000 bf16 -> ends 23857152
    __hip_bfloat16* h2b = (__hip_bfloat16*)(ws + 23857152);  // 320000 bf16 -> ends 24497152

    k_part_gemm1<<<PART_BLOCKS + GEMM_TILES, 256, 0, stream>>>(
        srcI, dstI, gcnt, partBuf, x, W1, h1b, bfc, out);
    k_bsort<<<NB, 512, 0, stream>>>(gcnt, partBuf, srcU, rowStart, dinv, h1b);
    k_gather1_gemm2<<<N_NODES / 8, 256, 0, stream>>>(h1b, rowStart, srcU,
                                                     dinv, b1, W2, h2b);
    k_gather2_out<<<N_NODES / 16, 256, 0, stream>>>(h2b, rowStart, srcU,
                                                    dinv, b2, Wfc, out);
}

// Round 3
// 147.809 us; speedup vs baseline: 4.2012x; 1.2486x over previous
//
#include <hip/hip_runtime.h>
#include <hip/hip_bf16.h>

#define N_NODES 10000
#define N_EDGES 640000
#define F_IN 128
#define H1 64
#define H2 32
#define N_CLASSES 16

#define MAXDEG 160      // deg ~ Binom(640k,1e-4): mean 64, sd 8 -> 160 = +12 sigma
#define PART_BLOCKS 625 // 625*256 int4 = 160000 exactly -> 1024 edges/block
#define GEMM_TILES 625  // 10000/16

typedef unsigned short ushortT;

__device__ __forceinline__ float bf_lo(unsigned u) {
    u <<= 16; float f; __builtin_memcpy(&f, &u, 4); return f;
}
__device__ __forceinline__ float bf_hi(unsigned u) {
    u &= 0xffff0000u; float f; __builtin_memcpy(&f, &u, 4); return f;
}
__device__ __forceinline__ unsigned bf_pack(float a, float b) {
    __hip_bfloat16 ha = __float2bfloat16(a), hb = __float2bfloat16(b);
    unsigned short ua, ub;
    __builtin_memcpy(&ua, &ha, 2); __builtin_memcpy(&ub, &hb, 2);
    return (unsigned)ua | ((unsigned)ub << 16);
}

// ---------- dispatch 1: edge scatter (blocks 0..624) + GEMM1 (625..1249) ----------
// scatter: adj[dst*MAXDEG + atomicAdd(&cnt[dst],1)] = (u16)src. Fixed-stride
//          adjacency rows -> NO sort, NO scan, NO rowStart. cnt zeroed by memset.
// gemm:    h1b = bf16(x @ W1), UNSCALED — dinv applied in-place by k_scale.
__global__ void __launch_bounds__(256) k_part_gemm1(const int* __restrict__ src,
                                                    const int* __restrict__ dst,
                                                    int* __restrict__ cnt,
                                                    ushortT* __restrict__ adj,
                                                    const float* __restrict__ x,
                                                    const float* __restrict__ W1,
                                                    __hip_bfloat16* __restrict__ h1b,
                                                    const float* __restrict__ bfc,
                                                    float* __restrict__ out) {
    __shared__ __align__(16) char pool[40960];  // gemm side only
    int t = threadIdx.x;
    if (blockIdx.x < PART_BLOCKS) {
        int g = blockIdx.x;
        const int4* src4 = (const int4*)src;
        const int4* dst4 = (const int4*)dst;
        int i4 = g * 256 + t;              // always < 160000
        int4 s = src4[i4];
        int4 d = dst4[i4];
        int p;
        p = atomicAdd(&cnt[d.x], 1); if (p < MAXDEG) adj[d.x * MAXDEG + p] = (ushortT)s.x;
        p = atomicAdd(&cnt[d.y], 1); if (p < MAXDEG) adj[d.y * MAXDEG + p] = (ushortT)s.y;
        p = atomicAdd(&cnt[d.z], 1); if (p < MAXDEG) adj[d.z * MAXDEG + p] = (ushortT)s.z;
        p = atomicAdd(&cnt[d.w], 1); if (p < MAXDEG) adj[d.w * MAXDEG + p] = (ushortT)s.w;
    } else {
        int gb = blockIdx.x - PART_BLOCKS;   // 0..624
        float* w1s = (float*)pool;           // [128][64] = 32 KB
        float* xs  = (float*)(pool + 32768); // [16][128] = 8 KB
        int node0 = gb * 16;                 // 625*16 = 10000 exact
        const float4* W14 = (const float4*)W1;
        float4* w1s4 = (float4*)w1s;
#pragma unroll
        for (int i = 0; i < 8; ++i) w1s4[i * 256 + t] = W14[i * 256 + t];
        const float4* x4 = (const float4*)(x + (long)node0 * F_IN);
        float4* xs4 = (float4*)xs;
#pragma unroll
        for (int i = 0; i < 2; ++i) xs4[i * 256 + t] = x4[i * 256 + t];
        if (gb == 0 && t < N_CLASSES) out[t] = bfc[t];  // seed output with bias
        __syncthreads();
        int j = t & 63;
        int q = t >> 6;       // wave id 0..3
        int r0 = q * 4;
        float acc0 = 0.f, acc1 = 0.f, acc2 = 0.f, acc3 = 0.f;
#pragma unroll 4
        for (int k = 0; k < F_IN; ++k) {
            float w = w1s[k * H1 + j];
            acc0 += xs[(r0 + 0) * F_IN + k] * w;
            acc1 += xs[(r0 + 1) * F_IN + k] * w;
            acc2 += xs[(r0 + 2) * F_IN + k] * w;
            acc3 += xs[(r0 + 3) * F_IN + k] * w;
        }
        int v0 = node0 + r0;
        h1b[(v0 + 0) * H1 + j] = __float2bfloat16(acc0);
        h1b[(v0 + 1) * H1 + j] = __float2bfloat16(acc1);
        h1b[(v0 + 2) * H1 + j] = __float2bfloat16(acc2);
        h1b[(v0 + 3) * H1 + j] = __float2bfloat16(acc3);
    }
}

// ---------- dispatch 2: dinv + in-place h1 scale (replaces 77us bsort) ----------
// 1250 blocks x 256 = 320000 threads, one bf16-pair (u32) each.
__global__ void __launch_bounds__(256) k_scale(const int* __restrict__ cnt,
                                               float* __restrict__ dinv,
                                               __hip_bfloat16* __restrict__ h1b) {
    int gid = blockIdx.x * 256 + threadIdx.x;   // < 320000 exact
    int v = gid >> 5, pp = gid & 31;
    float dv_ = rsqrtf((float)cnt[v] + 1.0f);   // true degree (unclamped count)
    if (pp == 0) dinv[v] = dv_;
    unsigned* h1u = (unsigned*)h1b;
    unsigned u = h1u[v * 32 + pp];
    h1u[v * 32 + pp] = bf_pack(bf_lo(u) * dv_, bf_hi(u) * dv_);
}

// ---------- dispatch 3: gather layer1 (fixed-stride adj, LDS-staged) + ReLU + GEMM2 ----------
// 1250 blocks x 256 threads = 8 nodes x 32 lanes; lane owns feature pair.
__global__ void __launch_bounds__(256) k_gather1_gemm2(const __hip_bfloat16* __restrict__ h1b,
                                const int* __restrict__ cnt,
                                const ushortT* __restrict__ adj,
                                const float* __restrict__ dinv,
                                const float* __restrict__ b1,
                                const float* __restrict__ W2,
                                __hip_bfloat16* __restrict__ h2b) {
    __shared__ float h1s[8][H1];            // 2 KB
    __shared__ ushortT idxs[8 * MAXDEG];    // 2.5 KB
    int t = threadIdx.x;
    int n  = t >> 5;        // node slot 0..7
    int fp = t & 31;        // feature pair
    int v0 = blockIdx.x * 8;
    int v = v0 + n;         // 1250*8 = 10000 exact
    // rows v0..v0+7 are contiguous: one coalesced 2560B stage
    const unsigned* a32 = (const unsigned*)(adj + (long)v0 * MAXDEG);
    unsigned* i32 = (unsigned*)idxs;
    for (int i = t; i < 8 * MAXDEG / 2; i += 256) i32[i] = a32[i];
    int deg = cnt[v]; if (deg > MAXDEG) deg = MAXDEG;
    float dv_ = dinv[v];
    const unsigned* h1u = (const unsigned*)h1b;
    unsigned su = h1u[v * 32 + fp];          // self-loop term (pre-scaled by dinv[v])
    float fx = bf_lo(su), fy = bf_hi(su);
    float x0 = 0.f, y0 = 0.f, x1 = 0.f, y1 = 0.f;
    float x2 = 0.f, y2 = 0.f, x3 = 0.f, y3 = 0.f;
    __syncthreads();
    const ushortT* myRow = &idxs[n * MAXDEG];
    int e = 0;
    for (; e + 4 <= deg; e += 4) {
        int i0 = myRow[e],     i1 = myRow[e + 1];
        int i2 = myRow[e + 2], i3 = myRow[e + 3];
        unsigned u0 = h1u[i0 * 32 + fp];
        unsigned u1 = h1u[i1 * 32 + fp];
        unsigned u2 = h1u[i2 * 32 + fp];
        unsigned u3 = h1u[i3 * 32 + fp];
        x0 += bf_lo(u0); y0 += bf_hi(u0);
        x1 += bf_lo(u1); y1 += bf_hi(u1);
        x2 += bf_lo(u2); y2 += bf_hi(u2);
        x3 += bf_lo(u3); y3 += bf_hi(u3);
    }
    for (; e < deg; ++e) {
        unsigned u = h1u[myRow[e] * 32 + fp];
        fx += bf_lo(u); fy += bf_hi(u);
    }
    fx += (x0 + x1) + (x2 + x3);
    fy += (y0 + y1) + (y2 + y3);
    ((float2*)h1s[n])[fp] = make_float2(fmaxf(dv_ * fx + b1[fp * 2], 0.f),
                                        fmaxf(dv_ * fy + b1[fp * 2 + 1], 0.f));
    __syncthreads();
    // GEMM2: thread = (node n, output j=fp in [0,32))
    float acc = 0.f;
#pragma unroll
    for (int kk = 0; kk < H1; ++kk)
        acc += h1s[n][kk] * W2[kk * H2 + fp];
    h2b[v * H2 + fp] = __float2bfloat16(acc * dv_);  // pre-scaled
}

// ---------- dispatch 4: gather layer2 + ReLU + partial mean + partial FC -> out ----------
// 625 blocks x 256 threads = 16 nodes x 16 lanes. out pre-seeded with bfc;
// each block atomically adds its partial (mean @ Wfc) — linear, so exact.
__global__ void __launch_bounds__(256) k_gather2_out(const __hip_bfloat16* __restrict__ h2b,
                               const int* __restrict__ cnt,
                               const ushortT* __restrict__ adj,
                               const float* __restrict__ dinv,
                               const float* __restrict__ b2,
                               const float* __restrict__ Wfc,
                               float* __restrict__ out) {
    __shared__ float red[16][H2];            // 2 KB
    __shared__ ushortT idxs[16 * MAXDEG];    // 5 KB
    __shared__ float gs[H2];
    int t = threadIdx.x;
    int n  = t >> 4;        // node slot 0..15
    int fp = t & 15;        // feature pair of H2
    int v0 = blockIdx.x * 16;
    int v = v0 + n;         // 625*16 = 10000 exact
    const unsigned* a32 = (const unsigned*)(adj + (long)v0 * MAXDEG);
    unsigned* i32 = (unsigned*)idxs;
    for (int i = t; i < 16 * MAXDEG / 2; i += 256) i32[i] = a32[i];
    int deg = cnt[v]; if (deg > MAXDEG) deg = MAXDEG;
    float dv_ = dinv[v];
    const unsigned* h2u = (const unsigned*)h2b;
    unsigned su = h2u[v * 16 + fp];          // self-loop term (pre-scaled)
    float fx = bf_lo(su), fy = bf_hi(su);
    float x0 = 0.f, y0 = 0.f, x1 = 0.f, y1 = 0.f;
    float x2 = 0.f, y2 = 0.f, x3 = 0.f, y3 = 0.f;
    __syncthreads();
    const ushortT* myRow = &idxs[n * MAXDEG];
    int e = 0;
    for (; e + 4 <= deg; e += 4) {
        int i0 = myRow[e],     i1 = myRow[e + 1];
        int i2 = myRow[e + 2], i3 = myRow[e + 3];
        unsigned u0 = h2u[i0 * 16 + fp];
        unsigned u1 = h2u[i1 * 16 + fp];
        unsigned u2 = h2u[i2 * 16 + fp];
        unsigned u3 = h2u[i3 * 16 + fp];
        x0 += bf_lo(u0); y0 += bf_hi(u0);
        x1 += bf_lo(u1); y1 += bf_hi(u1);
        x2 += bf_lo(u2); y2 += bf_hi(u2);
        x3 += bf_lo(u3); y3 += bf_hi(u3);
    }
    for (; e < deg; ++e) {
        unsigned u = h2u[myRow[e] * 16 + fp];
        fx += bf_lo(u); fy += bf_hi(u);
    }
    fx += (x0 + x1) + (x2 + x3);
    fy += (y0 + y1) + (y2 + y3);
    ((float2*)red[n])[fp] = make_float2(fmaxf(dv_ * fx + b2[fp * 2], 0.f),
                                        fmaxf(dv_ * fy + b2[fp * 2 + 1], 0.f));
    __syncthreads();
    if (t < H2) {
        float s = 0.f;
#pragma unroll
        for (int r = 0; r < 16; ++r) s += red[r][t];
        gs[t] = s;
    }
    __syncthreads();
    if (t < N_CLASSES) {
        float acc = 0.f;
#pragma unroll
        for (int j = 0; j < H2; ++j)
            acc += gs[j] * Wfc[j * N_CLASSES + t];
        atomicAdd(&out[t], acc * (1.0f / (float)N_NODES));
    }
}

extern "C" void kernel_launch(void* const* d_in, const int* in_sizes, int n_in,
                              void* d_out, int out_size, void* d_ws, size_t ws_size,
                              hipStream_t stream) {
    const float* x   = (const float*)d_in[0];
    const float* W1  = (const float*)d_in[1];
    const float* b1  = (const float*)d_in[2];
    const float* W2  = (const float*)d_in[3];
    const float* b2  = (const float*)d_in[4];
    const float* Wfc = (const float*)d_in[5];
    const float* bfc = (const float*)d_in[6];
    const int* edge  = (const int*)d_in[7];
    const int* srcI = edge;              // edge_index[0]
    const int* dstI = edge + N_EDGES;    // edge_index[1]
    float* out = (float*)d_out;

    // workspace layout (~5.2 MB). Only cnt needs zero-init (40 KB memset).
    char* ws = (char*)d_ws;
    int*     cnt  = (int*)    (ws + 0);        // 10240 ints (10000 used)
    float*   dinv = (float*)  (ws + 40960);    // 10000 f -> ends 80960
    ushortT* adj  = (ushortT*)(ws + 81920);    // 10000*160 u16 = 3.2MB -> ends 3281920
    __hip_bfloat16* h1b = (__hip_bfloat16*)(ws + 3281920);  // 640000 bf16 -> ends 4561920
    __hip_bfloat16* h2b = (__hip_bfloat16*)(ws + 4561920);  // 320000 bf16 -> ends 5201920

    hipMemsetAsync(cnt, 0, 40960, stream);

    k_part_gemm1<<<PART_BLOCKS + GEMM_TILES, 256, 0, stream>>>(
        srcI, dstI, cnt, adj, x, W1, h1b, bfc, out);
    k_scale<<<1250, 256, 0, stream>>>(cnt, dinv, h1b);
    k_gather1_gemm2<<<1250, 256, 0, stream>>>(h1b, cnt, adj, dinv, b1, W2, h2b);
    k_gather2_out<<<625, 256, 0, stream>>>(h2b, cnt, adj, dinv, b2, Wfc, out);
}

// Round 4
// 141.031 us; speedup vs baseline: 4.4031x; 1.0481x over previous
//
#include <hip/hip_runtime.h>
#include <hip/hip_bf16.h>

#define N_NODES 10000
#define N_EDGES 640000
#define F_IN 128
#define H1 64
#define H2 32
#define N_CLASSES 16

#define MAXDEG 160      // deg ~ Binom(640k,1e-4): mean 64, sd 8 -> 160 = +12 sigma
#define CPAD 16         // cnt stride: 1 counter per 64B line (atomic ping-pong fix)
#define GEMM_TILES 625  // 10000/16

typedef unsigned short ushortT;

__device__ __forceinline__ float bf_lo(unsigned u) {
    u <<= 16; float f; __builtin_memcpy(&f, &u, 4); return f;
}
__device__ __forceinline__ float bf_hi(unsigned u) {
    u &= 0xffff0000u; float f; __builtin_memcpy(&f, &u, 4); return f;
}

// ---------- dispatch 1: edge scatter ----------
// adj[dst*MAXDEG + atomicAdd(&cnt[dst*16],1)] = (u16)src.
// cnt padded to one counter per 64B cache line: per-line atomic chains drop
// 1024 -> 64, parallel over 10000 lines (cross-XCD ownership ping-pong fix).
// No LDS -> full wave occupancy; 1250 blocks x 256 thr x 2 edges.
__global__ void __launch_bounds__(256) k_scatter(const int* __restrict__ src,
                                                 const int* __restrict__ dst,
                                                 int* __restrict__ cnt,
                                                 ushortT* __restrict__ adj) {
    int i = blockIdx.x * 256 + threadIdx.x;   // < 320000 exact
    int2 s = ((const int2*)src)[i];
    int2 d = ((const int2*)dst)[i];
    int p;
    p = atomicAdd(&cnt[d.x * CPAD], 1);
    if (p < MAXDEG) adj[d.x * MAXDEG + p] = (ushortT)s.x;
    p = atomicAdd(&cnt[d.y * CPAD], 1);
    if (p < MAXDEG) adj[d.y * MAXDEG + p] = (ushortT)s.y;
}

// ---------- dispatch 2: GEMM1 + dinv fused ----------
// h1b = bf16(dinv[v] * (x @ W1)); also writes dinv[v]. cnt is final here
// (scatter dispatch completed), so scale is applied at creation: single
// bf16 rounding (was double via the old k_scale pass).
__global__ void __launch_bounds__(256) k_gemm1(const float* __restrict__ x,
                                               const float* __restrict__ W1,
                                               const int* __restrict__ cnt,
                                               float* __restrict__ dinv,
                                               __hip_bfloat16* __restrict__ h1b,
                                               const float* __restrict__ bfc,
                                               float* __restrict__ out) {
    __shared__ __align__(16) float w1s[F_IN * H1];   // 32 KB
    __shared__ __align__(16) float xs[16 * F_IN];    // 8 KB
    int t = threadIdx.x;
    int gb = blockIdx.x;                 // 0..624
    int node0 = gb * 16;                 // 625*16 = 10000 exact
    const float4* W14 = (const float4*)W1;
    float4* w1s4 = (float4*)w1s;
#pragma unroll
    for (int i = 0; i < 8; ++i) w1s4[i * 256 + t] = W14[i * 256 + t];
    const float4* x4 = (const float4*)(x + (long)node0 * F_IN);
    float4* xs4 = (float4*)xs;
#pragma unroll
    for (int i = 0; i < 2; ++i) xs4[i * 256 + t] = x4[i * 256 + t];
    if (gb == 0 && t < N_CLASSES) out[t] = bfc[t];  // seed output with bias
    __syncthreads();
    int j = t & 63;
    int q = t >> 6;       // wave id 0..3
    int r0 = q * 4;
    float acc0 = 0.f, acc1 = 0.f, acc2 = 0.f, acc3 = 0.f;
#pragma unroll 4
    for (int k = 0; k < F_IN; ++k) {
        float w = w1s[k * H1 + j];
        acc0 += xs[(r0 + 0) * F_IN + k] * w;
        acc1 += xs[(r0 + 1) * F_IN + k] * w;
        acc2 += xs[(r0 + 2) * F_IN + k] * w;
        acc3 += xs[(r0 + 3) * F_IN + k] * w;
    }
    int v0 = node0 + r0;
    float dv0 = rsqrtf((float)cnt[(v0 + 0) * CPAD] + 1.0f);
    float dv1 = rsqrtf((float)cnt[(v0 + 1) * CPAD] + 1.0f);
    float dv2 = rsqrtf((float)cnt[(v0 + 2) * CPAD] + 1.0f);
    float dv3 = rsqrtf((float)cnt[(v0 + 3) * CPAD] + 1.0f);
    if (j == 0) {
        dinv[v0 + 0] = dv0; dinv[v0 + 1] = dv1;
        dinv[v0 + 2] = dv2; dinv[v0 + 3] = dv3;
    }
    h1b[(v0 + 0) * H1 + j] = __float2bfloat16(acc0 * dv0);
    h1b[(v0 + 1) * H1 + j] = __float2bfloat16(acc1 * dv1);
    h1b[(v0 + 2) * H1 + j] = __float2bfloat16(acc2 * dv2);
    h1b[(v0 + 3) * H1 + j] = __float2bfloat16(acc3 * dv3);
}

// ---------- dispatch 3: gather layer1 (fixed-stride adj, LDS-staged) + ReLU + GEMM2 ----------
// 1250 blocks x 256 threads = 8 nodes x 32 lanes; lane owns feature pair.
__global__ void __launch_bounds__(256) k_gather1_gemm2(const __hip_bfloat16* __restrict__ h1b,
                                const int* __restrict__ cnt,
                                const ushortT* __restrict__ adj,
                                const float* __restrict__ dinv,
                                const float* __restrict__ b1,
                                const float* __restrict__ W2,
                                __hip_bfloat16* __restrict__ h2b) {
    __shared__ float h1s[8][H1];            // 2 KB
    __shared__ ushortT idxs[8 * MAXDEG];    // 2.5 KB
    int t = threadIdx.x;
    int n  = t >> 5;        // node slot 0..7
    int fp = t & 31;        // feature pair
    int v0 = blockIdx.x * 8;
    int v = v0 + n;         // 1250*8 = 10000 exact
    // rows v0..v0+7 are contiguous: one coalesced 2560B stage
    const unsigned* a32 = (const unsigned*)(adj + (long)v0 * MAXDEG);
    unsigned* i32 = (unsigned*)idxs;
    for (int i = t; i < 8 * MAXDEG / 2; i += 256) i32[i] = a32[i];
    int deg = cnt[v * CPAD]; if (deg > MAXDEG) deg = MAXDEG;
    float dv_ = dinv[v];
    const unsigned* h1u = (const unsigned*)h1b;
    unsigned su = h1u[v * 32 + fp];          // self-loop term (pre-scaled by dinv[v])
    float fx = bf_lo(su), fy = bf_hi(su);
    float x0 = 0.f, y0 = 0.f, x1 = 0.f, y1 = 0.f;
    float x2 = 0.f, y2 = 0.f, x3 = 0.f, y3 = 0.f;
    __syncthreads();
    const ushortT* myRow = &idxs[n * MAXDEG];
    int e = 0;
    for (; e + 4 <= deg; e += 4) {
        int i0 = myRow[e],     i1 = myRow[e + 1];
        int i2 = myRow[e + 2], i3 = myRow[e + 3];
        unsigned u0 = h1u[i0 * 32 + fp];
        unsigned u1 = h1u[i1 * 32 + fp];
        unsigned u2 = h1u[i2 * 32 + fp];
        unsigned u3 = h1u[i3 * 32 + fp];
        x0 += bf_lo(u0); y0 += bf_hi(u0);
        x1 += bf_lo(u1); y1 += bf_hi(u1);
        x2 += bf_lo(u2); y2 += bf_hi(u2);
        x3 += bf_lo(u3); y3 += bf_hi(u3);
    }
    for (; e < deg; ++e) {
        unsigned u = h1u[myRow[e] * 32 + fp];
        fx += bf_lo(u); fy += bf_hi(u);
    }
    fx += (x0 + x1) + (x2 + x3);
    fy += (y0 + y1) + (y2 + y3);
    ((float2*)h1s[n])[fp] = make_float2(fmaxf(dv_ * fx + b1[fp * 2], 0.f),
                                        fmaxf(dv_ * fy + b1[fp * 2 + 1], 0.f));
    __syncthreads();
    // GEMM2: thread = (node n, output j=fp in [0,32))
    float acc = 0.f;
#pragma unroll
    for (int kk = 0; kk < H1; ++kk)
        acc += h1s[n][kk] * W2[kk * H2 + fp];
    h2b[v * H2 + fp] = __float2bfloat16(acc * dv_);  // pre-scaled
}

// ---------- dispatch 4: gather layer2 + ReLU + partial mean + partial FC -> out ----------
// 625 blocks x 256 threads = 16 nodes x 16 lanes. out pre-seeded with bfc;
// each block atomically adds its partial (mean @ Wfc) — linear, so exact.
__global__ void __launch_bounds__(256) k_gather2_out(const __hip_bfloat16* __restrict__ h2b,
                               const int* __restrict__ cnt,
                               const ushortT* __restrict__ adj,
                               const float* __restrict__ dinv,
                               const float* __restrict__ b2,
                               const float* __restrict__ Wfc,
                               float* __restrict__ out) {
    __shared__ float red[16][H2];            // 2 KB
    __shared__ ushortT idxs[16 * MAXDEG];    // 5 KB
    __shared__ float gs[H2];
    int t = threadIdx.x;
    int n  = t >> 4;        // node slot 0..15
    int fp = t & 15;        // feature pair of H2
    int v0 = blockIdx.x * 16;
    int v = v0 + n;         // 625*16 = 10000 exact
    const unsigned* a32 = (const unsigned*)(adj + (long)v0 * MAXDEG);
    unsigned* i32 = (unsigned*)idxs;
    for (int i = t; i < 16 * MAXDEG / 2; i += 256) i32[i] = a32[i];
    int deg = cnt[v * CPAD]; if (deg > MAXDEG) deg = MAXDEG;
    float dv_ = dinv[v];
    const unsigned* h2u = (const unsigned*)h2b;
    unsigned su = h2u[v * 16 + fp];          // self-loop term (pre-scaled)
    float fx = bf_lo(su), fy = bf_hi(su);
    float x0 = 0.f, y0 = 0.f, x1 = 0.f, y1 = 0.f;
    float x2 = 0.f, y2 = 0.f, x3 = 0.f, y3 = 0.f;
    __syncthreads();
    const ushortT* myRow = &idxs[n * MAXDEG];
    int e = 0;
    for (; e + 4 <= deg; e += 4) {
        int i0 = myRow[e],     i1 = myRow[e + 1];
        int i2 = myRow[e + 2], i3 = myRow[e + 3];
        unsigned u0 = h2u[i0 * 16 + fp];
        unsigned u1 = h2u[i1 * 16 + fp];
        unsigned u2 = h2u[i2 * 16 + fp];
        unsigned u3 = h2u[i3 * 16 + fp];
        x0 += bf_lo(u0); y0 += bf_hi(u0);
        x1 += bf_lo(u1); y1 += bf_hi(u1);
        x2 += bf_lo(u2); y2 += bf_hi(u2);
        x3 += bf_lo(u3); y3 += bf_hi(u3);
    }
    for (; e < deg; ++e) {
        unsigned u = h2u[myRow[e] * 16 + fp];
        fx += bf_lo(u); fy += bf_hi(u);
    }
    fx += (x0 + x1) + (x2 + x3);
    fy += (y0 + y1) + (y2 + y3);
    ((float2*)red[n])[fp] = make_float2(fmaxf(dv_ * fx + b2[fp * 2], 0.f),
                                        fmaxf(dv_ * fy + b2[fp * 2 + 1], 0.f));
    __syncthreads();
    if (t < H2) {
        float s = 0.f;
#pragma unroll
        for (int r = 0; r < 16; ++r) s += red[r][t];
        gs[t] = s;
    }
    __syncthreads();
    if (t < N_CLASSES) {
        float acc = 0.f;
#pragma unroll
        for (int j = 0; j < H2; ++j)
            acc += gs[j] * Wfc[j * N_CLASSES + t];
        atomicAdd(&out[t], acc * (1.0f / (float)N_NODES));
    }
}

extern "C" void kernel_launch(void* const* d_in, const int* in_sizes, int n_in,
                              void* d_out, int out_size, void* d_ws, size_t ws_size,
                              hipStream_t stream) {
    const float* x   = (const float*)d_in[0];
    const float* W1  = (const float*)d_in[1];
    const float* b1  = (const float*)d_in[2];
    const float* W2  = (const float*)d_in[3];
    const float* b2  = (const float*)d_in[4];
    const float* Wfc = (const float*)d_in[5];
    const float* bfc = (const float*)d_in[6];
    const int* edge  = (const int*)d_in[7];
    const int* srcI = edge;              // edge_index[0]
    const int* dstI = edge + N_EDGES;    // edge_index[1]
    float* out = (float*)d_out;

    // workspace layout (~5.8 MB). Only cnt needs zero-init (640 KB memset).
    char* ws = (char*)d_ws;
    int*     cnt  = (int*)    (ws + 0);        // 10000*16 ints (line-padded) = 640 KB
    float*   dinv = (float*)  (ws + 655360);   // 10000 f -> ends 695360
    ushortT* adj  = (ushortT*)(ws + 696320);   // 10000*160 u16 = 3.2MB -> ends 3896320
    __hip_bfloat16* h1b = (__hip_bfloat16*)(ws + 3896320);  // 640000 bf16 -> ends 5176320
    __hip_bfloat16* h2b = (__hip_bfloat16*)(ws + 5176320);  // 320000 bf16 -> ends 5816320

    hipMemsetAsync(cnt, 0, 655360, stream);

    k_scatter<<<1250, 256, 0, stream>>>(srcI, dstI, cnt, adj);
    k_gemm1<<<GEMM_TILES, 256, 0, stream>>>(x, W1, cnt, dinv, h1b, bfc, out);
    k_gather1_gemm2<<<1250, 256, 0, stream>>>(h1b, cnt, adj, dinv, b1, W2, h2b);
    k_gather2_out<<<625, 256, 0, stream>>>(h2b, cnt, adj, dinv, b2, Wfc, out);
}

// Round 5
// 117.643 us; speedup vs baseline: 5.2785x; 1.1988x over previous
//
#include <hip/hip_runtime.h>
#include <hip/hip_bf16.h>

#define N_NODES 10000
#define N_EDGES 640000
#define F_IN 128
#define H1 64
#define H2 32
#define N_CLASSES 16

#define NB 256          // dst-range buckets
#define NPB 40          // nodes per bucket (256*40 = 10240 >= 10000; buckets 250+ empty)
#define STAGE_C 32      // per-(block,bucket) LDS staging cap: Binom(2048,1/256) mean 8, sd 2.8 -> +8.5 sigma; spill path below
#define SLOT 3072       // per-bucket partBuf capacity (mean 2500, ~+11 sigma)
#define PART_BLOCKS 313 // 313*2048 >= 640000 edges, 2048 edges/block
#define MAXDEG 160      // deg ~ Binom(640k,1e-4): mean 64, sd 8 -> +12 sigma
#define GEMM_TILES 625  // 10000/16

typedef unsigned short ushortT;

__device__ __forceinline__ float bf_lo(unsigned u) {
    u <<= 16; float f; __builtin_memcpy(&f, &u, 4); return f;
}
__device__ __forceinline__ float bf_hi(unsigned u) {
    u &= 0xffff0000u; float f; __builtin_memcpy(&f, &u, 4); return f;
}
__device__ __forceinline__ unsigned bf_pack(float a, float b) {
    __hip_bfloat16 ha = __float2bfloat16(a), hb = __float2bfloat16(b);
    unsigned short ua, ub;
    __builtin_memcpy(&ua, &ha, 2); __builtin_memcpy(&ub, &hb, 2);
    return (unsigned)ua | ((unsigned)ub << 16);
}

// ---------- dispatch 1: edge partition (blocks 0..312) + GEMM1 (313..937) ----------
// part: bin edges by dst-bucket in LDS (640k LDS atomics), then reserve dense
//       partBuf ranges with ONE global atomic per (block,bucket) (~80k total —
//       the 640k node-level device atomics of the old scatter were the 35us
//       bottleneck at ~7.6 atomics/cyc coherence-point throughput).
// gemm: h1b = bf16(x @ W1), UNSCALED — dinv applied in-place by k_place.
__global__ void __launch_bounds__(256) k_part_gemm1(const int* __restrict__ src,
                                                    const int* __restrict__ dst,
                                                    int* __restrict__ bucketTot,
                                                    int* __restrict__ partBuf,
                                                    const float* __restrict__ x,
                                                    const float* __restrict__ W1,
                                                    __hip_bfloat16* __restrict__ h1b,
                                                    const float* __restrict__ bfc,
                                                    float* __restrict__ out) {
    __shared__ __align__(16) char pool[40960];  // union: part 34KB / gemm 40KB
    int t = threadIdx.x;
    if (blockIdx.x < PART_BLOCKS) {
        int g = blockIdx.x;
        int* cnt   = (int*)pool;           // 256 ints
        int* gbase = (int*)(pool + 1024);  // 256 ints
        int* stage = (int*)(pool + 2048);  // 256*32 ints = 32 KB
        if (t < NB) cnt[t] = 0;
        __syncthreads();
        const int4* src4 = (const int4*)src;
        const int4* dst4 = (const int4*)dst;
#pragma unroll
        for (int k = 0; k < 2; ++k) {
            int i4 = g * 512 + k * 256 + t;
            if (i4 < N_EDGES / 4) {
                int4 s = src4[i4];
                int4 d = dst4[i4];
                int b, l, p, val;
                b = d.x / NPB; l = d.x - b * NPB; val = s.x | (l << 14);
                p = atomicAdd(&cnt[b], 1);
                if (p < STAGE_C) stage[(b << 5) + p] = val;
                else { int gp = atomicAdd(&bucketTot[b], 1); if (gp < SLOT) partBuf[b * SLOT + gp] = val; }
                b = d.y / NPB; l = d.y - b * NPB; val = s.y | (l << 14);
                p = atomicAdd(&cnt[b], 1);
                if (p < STAGE_C) stage[(b << 5) + p] = val;
                else { int gp = atomicAdd(&bucketTot[b], 1); if (gp < SLOT) partBuf[b * SLOT + gp] = val; }
                b = d.z / NPB; l = d.z - b * NPB; val = s.z | (l << 14);
                p = atomicAdd(&cnt[b], 1);
                if (p < STAGE_C) stage[(b << 5) + p] = val;
                else { int gp = atomicAdd(&bucketTot[b], 1); if (gp < SLOT) partBuf[b * SLOT + gp] = val; }
                b = d.w / NPB; l = d.w - b * NPB; val = s.w | (l << 14);
                p = atomicAdd(&cnt[b], 1);
                if (p < STAGE_C) stage[(b << 5) + p] = val;
                else { int gp = atomicAdd(&bucketTot[b], 1); if (gp < SLOT) partBuf[b * SLOT + gp] = val; }
            }
        }
        __syncthreads();
        if (t < NB) {
            int c = cnt[t]; if (c > STAGE_C) c = STAGE_C;
            gbase[t] = atomicAdd(&bucketTot[t], c);   // one reservation per (block,bucket)
            cnt[t] = c;
        }
        __syncthreads();
#pragma unroll
        for (int rep = 0; rep < (NB * STAGE_C) / 256; ++rep) {
            int i = rep * 256 + t;
            int b = i >> 5, k = i & 31;
            if (k < cnt[b]) {
                int gp = gbase[b] + k;
                if (gp < SLOT) partBuf[b * SLOT + gp] = stage[i];
            }
        }
    } else {
        int gb = blockIdx.x - PART_BLOCKS;   // 0..624
        float* w1s = (float*)pool;           // [128][64] = 32 KB
        float* xs  = (float*)(pool + 32768); // [16][128] = 8 KB
        int node0 = gb * 16;                 // 625*16 = 10000 exact
        const float4* W14 = (const float4*)W1;
        float4* w1s4 = (float4*)w1s;
#pragma unroll
        for (int i = 0; i < 8; ++i) w1s4[i * 256 + t] = W14[i * 256 + t];
        const float4* x4 = (const float4*)(x + (long)node0 * F_IN);
        float4* xs4 = (float4*)xs;
#pragma unroll
        for (int i = 0; i < 2; ++i) xs4[i * 256 + t] = x4[i * 256 + t];
        if (gb == 0 && t < N_CLASSES) out[t] = bfc[t];  // seed output with bias
        __syncthreads();
        int j = t & 63;
        int q = t >> 6;       // wave id 0..3
        int r0 = q * 4;
        float acc0 = 0.f, acc1 = 0.f, acc2 = 0.f, acc3 = 0.f;
#pragma unroll 4
        for (int k = 0; k < F_IN; ++k) {
            float w = w1s[k * H1 + j];
            acc0 += xs[(r0 + 0) * F_IN + k] * w;
            acc1 += xs[(r0 + 1) * F_IN + k] * w;
            acc2 += xs[(r0 + 2) * F_IN + k] * w;
            acc3 += xs[(r0 + 3) * F_IN + k] * w;
        }
        int v0 = node0 + r0;
        h1b[(v0 + 0) * H1 + j] = __float2bfloat16(acc0);
        h1b[(v0 + 1) * H1 + j] = __float2bfloat16(acc1);
        h1b[(v0 + 2) * H1 + j] = __float2bfloat16(acc2);
        h1b[(v0 + 3) * H1 + j] = __float2bfloat16(acc3);
    }
}

// ---------- dispatch 2: per-bucket place -> adj + cnt + dinv + in-place h1 scale ----------
// 256 blocks x 512. Bucket b owns nodes b*40..b*40+39; partBuf region is DENSE
// ([0, bucketTot[b])), so the sweep touches only real edges (the R2 mistake was
// a 12%-fill sparse sweep). All node-level cursors live in LDS.
__global__ void __launch_bounds__(512) k_place(const int* __restrict__ bucketTot,
                                               const int* __restrict__ partBuf,
                                               int* __restrict__ cnt,
                                               ushortT* __restrict__ adj,
                                               float* __restrict__ dinv,
                                               __hip_bfloat16* __restrict__ h1b) {
    __shared__ int ldeg[NPB];
    __shared__ int cur[NPB];
    __shared__ float sdv[NPB];
    int t = threadIdx.x;
    int b = blockIdx.x;
    int nodeBase = b * NPB;
    int nNodes = N_NODES - nodeBase;
    if (nNodes <= 0) return;           // buckets 250..255 empty
    if (nNodes > NPB) nNodes = NPB;
    int tot = bucketTot[b]; if (tot > SLOT) tot = SLOT;
    if (t < NPB) ldeg[t] = 0;
    __syncthreads();
    const int* myBuf = partBuf + b * SLOT;
    for (int i = t; i < tot; i += 512)
        atomicAdd(&ldeg[myBuf[i] >> 14], 1);
    __syncthreads();
    if (t < nNodes) {
        int v = nodeBase + t;
        int c = ldeg[t];
        cnt[v] = c;                    // plain store: single owner
        float dv_ = rsqrtf((float)c + 1.0f);
        dinv[v] = dv_;
        sdv[t] = dv_;
        cur[t] = 0;
    }
    __syncthreads();
    for (int i = t; i < tot; i += 512) {
        int p = myBuf[i];
        int ln = p >> 14;
        int pos = atomicAdd(&cur[ln], 1);
        if (pos < MAXDEG) adj[(nodeBase + ln) * MAXDEG + pos] = (ushortT)(p & 16383);
    }
    // scale this bucket's h1 rows by dinv, in place (bf16 pairs as u32)
    unsigned* h1u = (unsigned*)h1b;
    for (int i = t; i < nNodes * 32; i += 512) {
        int ln = i >> 5, pp = i & 31;
        int v = nodeBase + ln;
        unsigned u = h1u[v * 32 + pp];
        float d = sdv[ln];
        h1u[v * 32 + pp] = bf_pack(bf_lo(u) * d, bf_hi(u) * d);
    }
}

// ---------- dispatch 3: gather layer1 (fixed-stride adj, LDS-staged) + ReLU + GEMM2 ----------
// 1250 blocks x 256 threads = 8 nodes x 32 lanes; lane owns feature pair.
__global__ void __launch_bounds__(256) k_gather1_gemm2(const __hip_bfloat16* __restrict__ h1b,
                                const int* __restrict__ cnt,
                                const ushortT* __restrict__ adj,
                                const float* __restrict__ dinv,
                                const float* __restrict__ b1,
                                const float* __restrict__ W2,
                                __hip_bfloat16* __restrict__ h2b) {
    __shared__ float h1s[8][H1];            // 2 KB
    __shared__ ushortT idxs[8 * MAXDEG];    // 2.5 KB
    __shared__ float w2s[H1 * H2];          // 8 KB
    int t = threadIdx.x;
    int n  = t >> 5;        // node slot 0..7
    int fp = t & 31;        // feature pair
    int v0 = blockIdx.x * 8;
    int v = v0 + n;         // 1250*8 = 10000 exact
    // stage W2 (kills 64 global loads/thread in GEMM2)
    const float4* W24 = (const float4*)W2;
    float4* w2s4 = (float4*)w2s;
#pragma unroll
    for (int i = 0; i < 2; ++i) w2s4[i * 256 + t] = W24[i * 256 + t];
    // rows v0..v0+7 contiguous: one coalesced 2560B stage
    const unsigned* a32 = (const unsigned*)(adj + (long)v0 * MAXDEG);
    unsigned* i32 = (unsigned*)idxs;
    for (int i = t; i < 8 * MAXDEG / 2; i += 256) i32[i] = a32[i];
    int deg = cnt[v]; if (deg > MAXDEG) deg = MAXDEG;
    float dv_ = dinv[v];
    const unsigned* h1u = (const unsigned*)h1b;
    unsigned su = h1u[v * 32 + fp];          // self-loop term (pre-scaled by dinv[v])
    float fx = bf_lo(su), fy = bf_hi(su);
    float x0 = 0.f, y0 = 0.f, x1 = 0.f, y1 = 0.f;
    float x2 = 0.f, y2 = 0.f, x3 = 0.f, y3 = 0.f;
    __syncthreads();
    const ushortT* myRow = &idxs[n * MAXDEG];
    int e = 0;
    for (; e + 4 <= deg; e += 4) {
        int i0 = myRow[e],     i1 = myRow[e + 1];
        int i2 = myRow[e + 2], i3 = myRow[e + 3];
        unsigned u0 = h1u[i0 * 32 + fp];
        unsigned u1 = h1u[i1 * 32 + fp];
        unsigned u2 = h1u[i2 * 32 + fp];
        unsigned u3 = h1u[i3 * 32 + fp];
        x0 += bf_lo(u0); y0 += bf_hi(u0);
        x1 += bf_lo(u1); y1 += bf_hi(u1);
        x2 += bf_lo(u2); y2 += bf_hi(u2);
        x3 += bf_lo(u3); y3 += bf_hi(u3);
    }
    for (; e < deg; ++e) {
        unsigned u = h1u[myRow[e] * 32 + fp];
        fx += bf_lo(u); fy += bf_hi(u);
    }
    fx += (x0 + x1) + (x2 + x3);
    fy += (y0 + y1) + (y2 + y3);
    ((float2*)h1s[n])[fp] = make_float2(fmaxf(dv_ * fx + b1[fp * 2], 0.f),
                                        fmaxf(dv_ * fy + b1[fp * 2 + 1], 0.f));
    __syncthreads();
    // GEMM2: thread = (node n, output j=fp in [0,32))
    float acc = 0.f;
#pragma unroll
    for (int kk = 0; kk < H1; ++kk)
        acc += h1s[n][kk] * w2s[kk * H2 + fp];
    h2b[v * H2 + fp] = __float2bfloat16(acc * dv_);  // pre-scaled
}

// ---------- dispatch 4: gather layer2 + ReLU + partial mean + partial FC -> out ----------
// 625 blocks x 256 threads = 16 nodes x 16 lanes. out pre-seeded with bfc;
// each block atomically adds its partial (mean @ Wfc) — linear, so exact.
__global__ void __launch_bounds__(256) k_gather2_out(const __hip_bfloat16* __restrict__ h2b,
                               const int* __restrict__ cnt,
                               const ushortT* __restrict__ adj,
                               const float* __restrict__ dinv,
                               const float* __restrict__ b2,
                               const float* __restrict__ Wfc,
                               float* __restrict__ out) {
    __shared__ float red[16][H2];            // 2 KB
    __shared__ ushortT idxs[16 * MAXDEG];    // 5 KB
    __shared__ float gs[H2];
    int t = threadIdx.x;
    int n  = t >> 4;        // node slot 0..15
    int fp = t & 15;        // feature pair of H2
    int v0 = blockIdx.x * 16;
    int v = v0 + n;         // 625*16 = 10000 exact
    const unsigned* a32 = (const unsigned*)(adj + (long)v0 * MAXDEG);
    unsigned* i32 = (unsigned*)idxs;
    for (int i = t; i < 16 * MAXDEG / 2; i += 256) i32[i] = a32[i];
    int deg = cnt[v]; if (deg > MAXDEG) deg = MAXDEG;
    float dv_ = dinv[v];
    const unsigned* h2u = (const unsigned*)h2b;
    unsigned su = h2u[v * 16 + fp];          // self-loop term (pre-scaled)
    float fx = bf_lo(su), fy = bf_hi(su);
    float x0 = 0.f, y0 = 0.f, x1 = 0.f, y1 = 0.f;
    float x2 = 0.f, y2 = 0.f, x3 = 0.f, y3 = 0.f;
    __syncthreads();
    const ushortT* myRow = &idxs[n * MAXDEG];
    int e = 0;
    for (; e + 4 <= deg; e += 4) {
        int i0 = myRow[e],     i1 = myRow[e + 1];
        int i2 = myRow[e + 2], i3 = myRow[e + 3];
        unsigned u0 = h2u[i0 * 16 + fp];
        unsigned u1 = h2u[i1 * 16 + fp];
        unsigned u2 = h2u[i2 * 16 + fp];
        unsigned u3 = h2u[i3 * 16 + fp];
        x0 += bf_lo(u0); y0 += bf_hi(u0);
        x1 += bf_lo(u1); y1 += bf_hi(u1);
        x2 += bf_lo(u2); y2 += bf_hi(u2);
        x3 += bf_lo(u3); y3 += bf_hi(u3);
    }
    for (; e < deg; ++e) {
        unsigned u = h2u[myRow[e] * 16 + fp];
        fx += bf_lo(u); fy += bf_hi(u);
    }
    fx += (x0 + x1) + (x2 + x3);
    fy += (y0 + y1) + (y2 + y3);
    ((float2*)red[n])[fp] = make_float2(fmaxf(dv_ * fx + b2[fp * 2], 0.f),
                                        fmaxf(dv_ * fy + b2[fp * 2 + 1], 0.f));
    __syncthreads();
    if (t < H2) {
        float s = 0.f;
#pragma unroll
        for (int r = 0; r < 16; ++r) s += red[r][t];
        gs[t] = s;
    }
    __syncthreads();
    if (t < N_CLASSES) {
        float acc = 0.f;
#pragma unroll
        for (int j = 0; j < H2; ++j)
            acc += gs[j] * Wfc[j * N_CLASSES + t];
        atomicAdd(&out[t], acc * (1.0f / (float)N_NODES));
    }
}

extern "C" void kernel_launch(void* const* d_in, const int* in_sizes, int n_in,
                              void* d_out, int out_size, void* d_ws, size_t ws_size,
                              hipStream_t stream) {
    const float* x   = (const float*)d_in[0];
    const float* W1  = (const float*)d_in[1];
    const float* b1  = (const float*)d_in[2];
    const float* W2  = (const float*)d_in[3];
    const float* b2  = (const float*)d_in[4];
    const float* Wfc = (const float*)d_in[5];
    const float* bfc = (const float*)d_in[6];
    const int* edge  = (const int*)d_in[7];
    const int* srcI = edge;              // edge_index[0]
    const int* dstI = edge + N_EDGES;    // edge_index[1]
    float* out = (float*)d_out;

    // workspace layout (~8.4 MB). Only bucketTot needs zero-init (1 KB memset).
    char* ws = (char*)d_ws;
    int*     bucketTot = (int*)    (ws + 0);        // 256 ints
    int*     cnt       = (int*)    (ws + 1024);     // 10000 ints -> 41024
    float*   dinv      = (float*)  (ws + 41984);    // 10000 f -> 81984
    int*     partBuf   = (int*)    (ws + 82944);    // 256*3072 ints = 3 MB -> 3228672
    ushortT* adj       = (ushortT*)(ws + 3228672);  // 10000*160 u16 = 3.2 MB -> 6428672
    __hip_bfloat16* h1b = (__hip_bfloat16*)(ws + 6428672);  // 640000 bf16 -> 7708672
    __hip_bfloat16* h2b = (__hip_bfloat16*)(ws + 7708672);  // 320000 bf16 -> 8348672

    hipMemsetAsync(bucketTot, 0, 1024, stream);

    k_part_gemm1<<<PART_BLOCKS + GEMM_TILES, 256, 0, stream>>>(
        srcI, dstI, bucketTot, partBuf, x, W1, h1b, bfc, out);
    k_place<<<NB, 512, 0, stream>>>(bucketTot, partBuf, cnt, adj, dinv, h1b);
    k_gather1_gemm2<<<1250, 256, 0, stream>>>(h1b, cnt, adj, dinv, b1, W2, h2b);
    k_gather2_out<<<625, 256, 0, stream>>>(h2b, cnt, adj, dinv, b2, Wfc, out);
}

// Round 6
// 114.826 us; speedup vs baseline: 5.4080x; 1.0245x over previous
//
#include <hip/hip_runtime.h>
#include <hip/hip_bf16.h>

#define N_NODES 10000
#define N_EDGES 640000
#define F_IN 128
#define H1 64
#define H2 32
#define N_CLASSES 16

#define NB 256          // dst-range buckets
#define NPB 40          // nodes per bucket; 250 place blocks x 40 = 10000 exact
#define STAGE_C 32      // per-(block,bucket) region cap: Binom(2048,1/256) mean 8 -> +8.5 sigma
#define PART_BLOCKS 313 // 313*2048 >= 640000 edges
#define CAP 3072        // per-bucket dense edge cap (mean 2500, +11 sigma)
#define MAXDEG 128      // deg ~ Binom(640k,1e-4): mean 64, sd 8; max over 10k nodes ~98
#define GEMM_TILES 625  // 10000/16

typedef unsigned short ushortT;

__device__ __forceinline__ float bf_lo(unsigned u) {
    u <<= 16; float f; __builtin_memcpy(&f, &u, 4); return f;
}
__device__ __forceinline__ float bf_hi(unsigned u) {
    u &= 0xffff0000u; float f; __builtin_memcpy(&f, &u, 4); return f;
}
__device__ __forceinline__ unsigned bf_pack(float a, float b) {
    __hip_bfloat16 ha = __float2bfloat16(a), hb = __float2bfloat16(b);
    unsigned short ua, ub;
    __builtin_memcpy(&ua, &ha, 2); __builtin_memcpy(&ub, &hb, 2);
    return (unsigned)ua | ((unsigned)ub << 16);
}

// ---------- dispatch 1: edge partition (blocks 0..312) + GEMM1 (313..937) ----------
// part: bin edges by dst-bucket in LDS, then write per-(block,bucket) fixed
//       regions + unconditional gcnt counts. ZERO global atomics, ZERO memset
//       (adj is fixed-stride per node, so no cross-bucket prefix is needed and
//       the dense-pack global cursor of R5 is unnecessary).
// gemm: h1b = bf16(x @ W1), UNSCALED — dinv applied in-place by k_place.
__global__ void __launch_bounds__(256) k_part_gemm1(const int* __restrict__ src,
                                                    const int* __restrict__ dst,
                                                    int* __restrict__ gcnt,
                                                    int* __restrict__ partBuf,
                                                    const float* __restrict__ x,
                                                    const float* __restrict__ W1,
                                                    __hip_bfloat16* __restrict__ h1b,
                                                    const float* __restrict__ bfc,
                                                    float* __restrict__ out) {
    __shared__ __align__(16) char pool[40960];  // union: part 33KB / gemm 40KB
    int t = threadIdx.x;
    if (blockIdx.x < PART_BLOCKS) {
        int g = blockIdx.x;
        int* cnt   = (int*)pool;           // 256 ints
        int* stage = (int*)(pool + 1024);  // 256*32 ints = 32 KB
        if (t < NB) cnt[t] = 0;
        __syncthreads();
        const int4* src4 = (const int4*)src;
        const int4* dst4 = (const int4*)dst;
#pragma unroll
        for (int k = 0; k < 2; ++k) {
            int i4 = g * 512 + k * 256 + t;
            if (i4 < N_EDGES / 4) {
                int4 s = src4[i4];
                int4 d = dst4[i4];
                int b, l, p;
                b = d.x / NPB; l = d.x - b * NPB; p = atomicAdd(&cnt[b], 1);
                if (p < STAGE_C) stage[(b << 5) + p] = s.x | (l << 14);
                b = d.y / NPB; l = d.y - b * NPB; p = atomicAdd(&cnt[b], 1);
                if (p < STAGE_C) stage[(b << 5) + p] = s.y | (l << 14);
                b = d.z / NPB; l = d.z - b * NPB; p = atomicAdd(&cnt[b], 1);
                if (p < STAGE_C) stage[(b << 5) + p] = s.z | (l << 14);
                b = d.w / NPB; l = d.w - b * NPB; p = atomicAdd(&cnt[b], 1);
                if (p < STAGE_C) stage[(b << 5) + p] = s.w | (l << 14);
            }
        }
        __syncthreads();
        if (t < NB) {
            int c = cnt[t]; if (c > STAGE_C) c = STAGE_C;  // memory-safety clamp
            cnt[t] = c;
            gcnt[g * NB + t] = c;          // coalesced, unconditional -> no init
        }
        __syncthreads();
#pragma unroll
        for (int rep = 0; rep < (NB * STAGE_C) / 256; ++rep) {
            int i = rep * 256 + t;
            int b = i >> 5, k = i & 31;
            if (k < cnt[b]) partBuf[(b * PART_BLOCKS + g) * STAGE_C + k] = stage[i];
        }
    } else {
        int gb = blockIdx.x - PART_BLOCKS;   // 0..624
        float* w1s = (float*)pool;           // [128][64] = 32 KB
        float* xs  = (float*)(pool + 32768); // [16][128] = 8 KB
        int node0 = gb * 16;                 // 625*16 = 10000 exact
        const float4* W14 = (const float4*)W1;
        float4* w1s4 = (float4*)w1s;
#pragma unroll
        for (int i = 0; i < 8; ++i) w1s4[i * 256 + t] = W14[i * 256 + t];
        const float4* x4 = (const float4*)(x + (long)node0 * F_IN);
        float4* xs4 = (float4*)xs;
#pragma unroll
        for (int i = 0; i < 2; ++i) xs4[i * 256 + t] = x4[i * 256 + t];
        if (gb == 0 && t < N_CLASSES) out[t] = bfc[t];  // seed output with bias
        __syncthreads();
        int j = t & 63;
        int q = t >> 6;       // wave id 0..3
        int r0 = q * 4;
        float acc0 = 0.f, acc1 = 0.f, acc2 = 0.f, acc3 = 0.f;
#pragma unroll 4
        for (int k = 0; k < F_IN; ++k) {
            float w = w1s[k * H1 + j];
            acc0 += xs[(r0 + 0) * F_IN + k] * w;
            acc1 += xs[(r0 + 1) * F_IN + k] * w;
            acc2 += xs[(r0 + 2) * F_IN + k] * w;
            acc3 += xs[(r0 + 3) * F_IN + k] * w;
        }
        int v0 = node0 + r0;
        h1b[(v0 + 0) * H1 + j] = __float2bfloat16(acc0);
        h1b[(v0 + 1) * H1 + j] = __float2bfloat16(acc1);
        h1b[(v0 + 2) * H1 + j] = __float2bfloat16(acc2);
        h1b[(v0 + 3) * H1 + j] = __float2bfloat16(acc3);
    }
}

// ---------- dispatch 2: per-bucket compact + place -> adj/cnt/dinv + h1 scale ----------
// 250 blocks x 512. Block b: stage count column scnt[313], LDS prefix scan,
// COMPACT sparse regions into dense LDS edge array (thread g copies region g to
// pre[g] — the dense-consumer fix), then count/place/scale. No global atomics.
__global__ void __launch_bounds__(512) k_place(const int* __restrict__ gcnt,
                                               const int* __restrict__ partBuf,
                                               int* __restrict__ cnt,
                                               ushortT* __restrict__ adj,
                                               float* __restrict__ dinv,
                                               __hip_bfloat16* __restrict__ h1b) {
    __shared__ int scnt[PART_BLOCKS];
    __shared__ int pre[PART_BLOCKS + 1];
    __shared__ int dense[CAP];
    __shared__ int ldeg[NPB];
    __shared__ int cur[NPB];
    __shared__ float sdv[NPB];
    int t = threadIdx.x;
    int b = blockIdx.x;                 // 0..249, nodeBase+39 <= 9999 always
    int nodeBase = b * NPB;
    if (t < PART_BLOCKS) scnt[t] = gcnt[t * NB + b];
    if (t < NPB) ldeg[t] = 0;
    __syncthreads();
    if (t < PART_BLOCKS) pre[t + 1] = scnt[t];
    if (t == 0) pre[0] = 0;
    __syncthreads();
    for (int off = 1; off < PART_BLOCKS; off <<= 1) {
        int v = 0;
        if (t >= off && t < PART_BLOCKS) v = pre[t + 1 - off];
        __syncthreads();
        if (t >= off && t < PART_BLOCKS) pre[t + 1] += v;
        __syncthreads();
    }
    int tot = pre[PART_BLOCKS]; if (tot > CAP) tot = CAP;
    // compact: thread g copies its region (mean 8, max 32 edges) to dense[pre[g]..]
    if (t < PART_BLOCKS) {
        int c = scnt[t], base = pre[t];
        const int* rp = partBuf + (b * PART_BLOCKS + t) * STAGE_C;
        for (int k = 0; k < c; ++k) {
            int dd = base + k;
            if (dd < CAP) dense[dd] = rp[k];
        }
    }
    __syncthreads();
    for (int i = t; i < tot; i += 512)
        atomicAdd(&ldeg[dense[i] >> 14], 1);
    __syncthreads();
    if (t < NPB) {
        int v = nodeBase + t;
        int c = ldeg[t];
        cnt[v] = c;                    // plain store: single owner
        float dv_ = rsqrtf((float)c + 1.0f);
        dinv[v] = dv_;
        sdv[t] = dv_;
        cur[t] = 0;
    }
    __syncthreads();
    for (int i = t; i < tot; i += 512) {
        int p = dense[i];
        int ln = p >> 14;
        int pos = atomicAdd(&cur[ln], 1);
        if (pos < MAXDEG) adj[(nodeBase + ln) * MAXDEG + pos] = (ushortT)(p & 16383);
    }
    // scale this bucket's h1 rows by dinv, in place (bf16 pairs as u32)
    unsigned* h1u = (unsigned*)h1b;
    for (int i = t; i < NPB * 32; i += 512) {
        int ln = i >> 5, pp = i & 31;
        int v = nodeBase + ln;
        unsigned u = h1u[v * 32 + pp];
        float d = sdv[ln];
        h1u[v * 32 + pp] = bf_pack(bf_lo(u) * d, bf_hi(u) * d);
    }
}

// ---------- dispatch 3: gather layer1 (fixed-stride adj, LDS-staged) + ReLU + GEMM2 ----------
// 1250 blocks x 256 threads = 8 nodes x 32 lanes; lane owns feature pair.
__global__ void __launch_bounds__(256) k_gather1_gemm2(const __hip_bfloat16* __restrict__ h1b,
                                const int* __restrict__ cnt,
                                const ushortT* __restrict__ adj,
                                const float* __restrict__ dinv,
                                const float* __restrict__ b1,
                                const float* __restrict__ W2,
                                __hip_bfloat16* __restrict__ h2b) {
    __shared__ float h1s[8][H1];            // 2 KB
    __shared__ ushortT idxs[8 * MAXDEG];    // 2 KB
    __shared__ float w2s[H1 * H2];          // 8 KB
    int t = threadIdx.x;
    int n  = t >> 5;        // node slot 0..7
    int fp = t & 31;        // feature pair
    int v0 = blockIdx.x * 8;
    int v = v0 + n;         // 1250*8 = 10000 exact
    // stage W2 (kills 64 global loads/thread in GEMM2)
    const float4* W24 = (const float4*)W2;
    float4* w2s4 = (float4*)w2s;
#pragma unroll
    for (int i = 0; i < 2; ++i) w2s4[i * 256 + t] = W24[i * 256 + t];
    // rows v0..v0+7 contiguous: one coalesced 2KB stage
    const unsigned* a32 = (const unsigned*)(adj + (long)v0 * MAXDEG);
    unsigned* i32 = (unsigned*)idxs;
#pragma unroll
    for (int i = 0; i < 2; ++i) i32[i * 256 + t] = a32[i * 256 + t];
    int deg = cnt[v]; if (deg > MAXDEG) deg = MAXDEG;
    float dv_ = dinv[v];
    const unsigned* h1u = (const unsigned*)h1b;
    unsigned su = h1u[v * 32 + fp];          // self-loop term (pre-scaled by dinv[v])
    float fx = bf_lo(su), fy = bf_hi(su);
    float x0 = 0.f, y0 = 0.f, x1 = 0.f, y1 = 0.f;
    float x2 = 0.f, y2 = 0.f, x3 = 0.f, y3 = 0.f;
    __syncthreads();
    const ushortT* myRow = &idxs[n * MAXDEG];
    int e = 0;
    for (; e + 8 <= deg; e += 8) {          // 8 loads in flight per round
        int i0 = myRow[e],     i1 = myRow[e + 1];
        int i2 = myRow[e + 2], i3 = myRow[e + 3];
        int i4 = myRow[e + 4], i5 = myRow[e + 5];
        int i6 = myRow[e + 6], i7 = myRow[e + 7];
        unsigned u0 = h1u[i0 * 32 + fp];
        unsigned u1 = h1u[i1 * 32 + fp];
        unsigned u2 = h1u[i2 * 32 + fp];
        unsigned u3 = h1u[i3 * 32 + fp];
        unsigned u4 = h1u[i4 * 32 + fp];
        unsigned u5 = h1u[i5 * 32 + fp];
        unsigned u6 = h1u[i6 * 32 + fp];
        unsigned u7 = h1u[i7 * 32 + fp];
        x0 += bf_lo(u0); y0 += bf_hi(u0);
        x1 += bf_lo(u1); y1 += bf_hi(u1);
        x2 += bf_lo(u2); y2 += bf_hi(u2);
        x3 += bf_lo(u3); y3 += bf_hi(u3);
        x0 += bf_lo(u4); y0 += bf_hi(u4);
        x1 += bf_lo(u5); y1 += bf_hi(u5);
        x2 += bf_lo(u6); y2 += bf_hi(u6);
        x3 += bf_lo(u7); y3 += bf_hi(u7);
    }
    for (; e < deg; ++e) {
        unsigned u = h1u[myRow[e] * 32 + fp];
        fx += bf_lo(u); fy += bf_hi(u);
    }
    fx += (x0 + x1) + (x2 + x3);
    fy += (y0 + y1) + (y2 + y3);
    ((float2*)h1s[n])[fp] = make_float2(fmaxf(dv_ * fx + b1[fp * 2], 0.f),
                                        fmaxf(dv_ * fy + b1[fp * 2 + 1], 0.f));
    __syncthreads();
    // GEMM2: thread = (node n, output j=fp in [0,32))
    float acc = 0.f;
#pragma unroll
    for (int kk = 0; kk < H1; ++kk)
        acc += h1s[n][kk] * w2s[kk * H2 + fp];
    h2b[v * H2 + fp] = __float2bfloat16(acc * dv_);  // pre-scaled
}

// ---------- dispatch 4: gather layer2 + ReLU + partial mean + partial FC -> out ----------
// 625 blocks x 256 threads = 16 nodes x 16 lanes. out pre-seeded with bfc;
// each block atomically adds its partial (mean @ Wfc) — linear, so exact.
__global__ void __launch_bounds__(256) k_gather2_out(const __hip_bfloat16* __restrict__ h2b,
                               const int* __restrict__ cnt,
                               const ushortT* __restrict__ adj,
                               const float* __restrict__ dinv,
                               const float* __restrict__ b2,
                               const float* __restrict__ Wfc,
                               float* __restrict__ out) {
    __shared__ float red[16][H2];            // 2 KB
    __shared__ ushortT idxs[16 * MAXDEG];    // 4 KB
    __shared__ float gs[H2];
    int t = threadIdx.x;
    int n  = t >> 4;        // node slot 0..15
    int fp = t & 15;        // feature pair of H2
    int v0 = blockIdx.x * 16;
    int v = v0 + n;         // 625*16 = 10000 exact
    const unsigned* a32 = (const unsigned*)(adj + (long)v0 * MAXDEG);
    unsigned* i32 = (unsigned*)idxs;
#pragma unroll
    for (int i = 0; i < 4; ++i) i32[i * 256 + t] = a32[i * 256 + t];
    int deg = cnt[v]; if (deg > MAXDEG) deg = MAXDEG;
    float dv_ = dinv[v];
    const unsigned* h2u = (const unsigned*)h2b;
    unsigned su = h2u[v * 16 + fp];          // self-loop term (pre-scaled)
    float fx = bf_lo(su), fy = bf_hi(su);
    float x0 = 0.f, y0 = 0.f, x1 = 0.f, y1 = 0.f;
    float x2 = 0.f, y2 = 0.f, x3 = 0.f, y3 = 0.f;
    __syncthreads();
    const ushortT* myRow = &idxs[n * MAXDEG];
    int e = 0;
    for (; e + 8 <= deg; e += 8) {
        int i0 = myRow[e],     i1 = myRow[e + 1];
        int i2 = myRow[e + 2], i3 = myRow[e + 3];
        int i4 = myRow[e + 4], i5 = myRow[e + 5];
        int i6 = myRow[e + 6], i7 = myRow[e + 7];
        unsigned u0 = h2u[i0 * 16 + fp];
        unsigned u1 = h2u[i1 * 16 + fp];
        unsigned u2 = h2u[i2 * 16 + fp];
        unsigned u3 = h2u[i3 * 16 + fp];
        unsigned u4 = h2u[i4 * 16 + fp];
        unsigned u5 = h2u[i5 * 16 + fp];
        unsigned u6 = h2u[i6 * 16 + fp];
        unsigned u7 = h2u[i7 * 16 + fp];
        x0 += bf_lo(u0); y0 += bf_hi(u0);
        x1 += bf_lo(u1); y1 += bf_hi(u1);
        x2 += bf_lo(u2); y2 += bf_hi(u2);
        x3 += bf_lo(u3); y3 += bf_hi(u3);
        x0 += bf_lo(u4); y0 += bf_hi(u4);
        x1 += bf_lo(u5); y1 += bf_hi(u5);
        x2 += bf_lo(u6); y2 += bf_hi(u6);
        x3 += bf_lo(u7); y3 += bf_hi(u7);
    }
    for (; e < deg; ++e) {
        unsigned u = h2u[myRow[e] * 16 + fp];
        fx += bf_lo(u); fy += bf_hi(u);
    }
    fx += (x0 + x1) + (x2 + x3);
    fy += (y0 + y1) + (y2 + y3);
    ((float2*)red[n])[fp] = make_float2(fmaxf(dv_ * fx + b2[fp * 2], 0.f),
                                        fmaxf(dv_ * fy + b2[fp * 2 + 1], 0.f));
    __syncthreads();
    if (t < H2) {
        float s = 0.f;
#pragma unroll
        for (int r = 0; r < 16; ++r) s += red[r][t];
        gs[t] = s;
    }
    __syncthreads();
    if (t < N_CLASSES) {
        float acc = 0.f;
#pragma unroll
        for (int j = 0; j < H2; ++j)
            acc += gs[j] * Wfc[j * N_CLASSES + t];
        atomicAdd(&out[t], acc * (1.0f / (float)N_NODES));
    }
}

extern "C" void kernel_launch(void* const* d_in, const int* in_sizes, int n_in,
                              void* d_out, int out_size, void* d_ws, size_t ws_size,
                              hipStream_t stream) {
    const float* x   = (const float*)d_in[0];
    const float* W1  = (const float*)d_in[1];
    const float* b1  = (const float*)d_in[2];
    const float* W2  = (const float*)d_in[3];
    const float* b2  = (const float*)d_in[4];
    const float* Wfc = (const float*)d_in[5];
    const float* bfc = (const float*)d_in[6];
    const int* edge  = (const int*)d_in[7];
    const int* srcI = edge;              // edge_index[0]
    const int* dstI = edge + N_EDGES;    // edge_index[1]
    float* out = (float*)d_out;

    // workspace layout (~15.2 MB). NO init required anywhere (gcnt written
    // unconditionally; adj slots beyond degree never read).
    char* ws = (char*)d_ws;
    int*     gcnt    = (int*)    (ws + 0);         // 313*256 ints = 320512 B
    int*     cnt     = (int*)    (ws + 321536);    // 10000 ints
    float*   dinv    = (float*)  (ws + 362496);    // 10000 f
    int*     partBuf = (int*)    (ws + 403456);    // 256*313*32 ints = 10256384 B
    ushortT* adj     = (ushortT*)(ws + 10659840);  // 10000*128 u16 = 2560000 B
    __hip_bfloat16* h1b = (__hip_bfloat16*)(ws + 13219840);  // 640000 bf16
    __hip_bfloat16* h2b = (__hip_bfloat16*)(ws + 14499840);  // 320000 bf16 -> 15139840

    k_part_gemm1<<<PART_BLOCKS + GEMM_TILES, 256, 0, stream>>>(
        srcI, dstI, gcnt, partBuf, x, W1, h1b, bfc, out);
    k_place<<<250, 512, 0, stream>>>(gcnt, partBuf, cnt, adj, dinv, h1b);
    k_gather1_gemm2<<<1250, 256, 0, stream>>>(h1b, cnt, adj, dinv, b1, W2, h2b);
    k_gather2_out<<<625, 256, 0, stream>>>(h2b, cnt, adj, dinv, b2, Wfc, out);
}

// Round 7
// 111.830 us; speedup vs baseline: 5.5528x; 1.0268x over previous
//
#include <hip/hip_runtime.h>
#include <hip/hip_bf16.h>

#define N_NODES 10000
#define N_EDGES 640000
#define F_IN 128
#define H1 64
#define H2 32
#define N_CLASSES 16

#define NB 256          // dst-range buckets
#define NPB 40          // nodes per bucket; 250 place blocks x 40 = 10000 exact
#define STAGE_C 32      // per-(block,bucket) region cap: Binom(2048,1/256) mean 8 -> +8.5 sigma
#define PART_BLOCKS 313 // 313*2048 >= 640000 edges
#define CAP 3072        // per-bucket dense edge cap (mean 2500, +11 sigma)
#define MAXDEG 128      // deg ~ Binom(640k,1e-4): mean 64, sd 8; max over 10k nodes ~98
#define GEMM_TILES 625  // 10000/16

typedef unsigned short ushortT;
typedef unsigned long long u64T;

__device__ __forceinline__ float bf_lo(unsigned u) {
    u <<= 16; float f; __builtin_memcpy(&f, &u, 4); return f;
}
__device__ __forceinline__ float bf_hi(unsigned u) {
    u &= 0xffff0000u; float f; __builtin_memcpy(&f, &u, 4); return f;
}
__device__ __forceinline__ unsigned bf_pack(float a, float b) {
    __hip_bfloat16 ha = __float2bfloat16(a), hb = __float2bfloat16(b);
    unsigned short ua, ub;
    __builtin_memcpy(&ua, &ha, 2); __builtin_memcpy(&ub, &hb, 2);
    return (unsigned)ua | ((unsigned)ub << 16);
}

// ---------- dispatch 1: edge partition (blocks 0..312) + GEMM1 (313..937) ----------
// part: bin edges by dst-bucket in LDS, write per-(block,bucket) fixed regions +
//       unconditional gcnt counts. ZERO global atomics, ZERO memset.
// gemm: h1b = bf16(x @ W1), UNSCALED — dinv applied in-place by k_place.
__global__ void __launch_bounds__(256) k_part_gemm1(const int* __restrict__ src,
                                                    const int* __restrict__ dst,
                                                    int* __restrict__ gcnt,
                                                    int* __restrict__ partBuf,
                                                    const float* __restrict__ x,
                                                    const float* __restrict__ W1,
                                                    __hip_bfloat16* __restrict__ h1b,
                                                    const float* __restrict__ bfc,
                                                    float* __restrict__ out) {
    __shared__ __align__(16) char pool[40960];  // union: part 33KB / gemm 40KB
    int t = threadIdx.x;
    if (blockIdx.x < PART_BLOCKS) {
        int g = blockIdx.x;
        int* cnt   = (int*)pool;           // 256 ints
        int* stage = (int*)(pool + 1024);  // 256*32 ints = 32 KB
        if (t < NB) cnt[t] = 0;
        __syncthreads();
        const int4* src4 = (const int4*)src;
        const int4* dst4 = (const int4*)dst;
#pragma unroll
        for (int k = 0; k < 2; ++k) {
            int i4 = g * 512 + k * 256 + t;
            if (i4 < N_EDGES / 4) {
                int4 s = src4[i4];
                int4 d = dst4[i4];
                int b, l, p;
                b = d.x / NPB; l = d.x - b * NPB; p = atomicAdd(&cnt[b], 1);
                if (p < STAGE_C) stage[(b << 5) + p] = s.x | (l << 14);
                b = d.y / NPB; l = d.y - b * NPB; p = atomicAdd(&cnt[b], 1);
                if (p < STAGE_C) stage[(b << 5) + p] = s.y | (l << 14);
                b = d.z / NPB; l = d.z - b * NPB; p = atomicAdd(&cnt[b], 1);
                if (p < STAGE_C) stage[(b << 5) + p] = s.z | (l << 14);
                b = d.w / NPB; l = d.w - b * NPB; p = atomicAdd(&cnt[b], 1);
                if (p < STAGE_C) stage[(b << 5) + p] = s.w | (l << 14);
            }
        }
        __syncthreads();
        if (t < NB) {
            int c = cnt[t]; if (c > STAGE_C) c = STAGE_C;  // memory-safety clamp
            cnt[t] = c;
            gcnt[g * NB + t] = c;          // coalesced, unconditional -> no init
        }
        __syncthreads();
#pragma unroll
        for (int rep = 0; rep < (NB * STAGE_C) / 256; ++rep) {
            int i = rep * 256 + t;
            int b = i >> 5, k = i & 31;
            if (k < cnt[b]) partBuf[(b * PART_BLOCKS + g) * STAGE_C + k] = stage[i];
        }
    } else {
        int gb = blockIdx.x - PART_BLOCKS;   // 0..624
        float* w1s = (float*)pool;           // [128][64] = 32 KB
        float* xs  = (float*)(pool + 32768); // [16][128] = 8 KB
        int node0 = gb * 16;                 // 625*16 = 10000 exact
        const float4* W14 = (const float4*)W1;
        float4* w1s4 = (float4*)w1s;
#pragma unroll
        for (int i = 0; i < 8; ++i) w1s4[i * 256 + t] = W14[i * 256 + t];
        const float4* x4 = (const float4*)(x + (long)node0 * F_IN);
        float4* xs4 = (float4*)xs;
#pragma unroll
        for (int i = 0; i < 2; ++i) xs4[i * 256 + t] = x4[i * 256 + t];
        if (gb == 0 && t < N_CLASSES) out[t] = bfc[t];  // seed output with bias
        __syncthreads();
        int j = t & 63;
        int q = t >> 6;       // wave id 0..3
        int r0 = q * 4;
        float acc0 = 0.f, acc1 = 0.f, acc2 = 0.f, acc3 = 0.f;
#pragma unroll 4
        for (int k = 0; k < F_IN; ++k) {
            float w = w1s[k * H1 + j];
            acc0 += xs[(r0 + 0) * F_IN + k] * w;
            acc1 += xs[(r0 + 1) * F_IN + k] * w;
            acc2 += xs[(r0 + 2) * F_IN + k] * w;
            acc3 += xs[(r0 + 3) * F_IN + k] * w;
        }
        int v0 = node0 + r0;
        h1b[(v0 + 0) * H1 + j] = __float2bfloat16(acc0);
        h1b[(v0 + 1) * H1 + j] = __float2bfloat16(acc1);
        h1b[(v0 + 2) * H1 + j] = __float2bfloat16(acc2);
        h1b[(v0 + 3) * H1 + j] = __float2bfloat16(acc3);
    }
}

// ---------- dispatch 2: per-bucket compact + place -> adj/cnt/dinv + h1 scale ----------
__global__ void __launch_bounds__(512) k_place(const int* __restrict__ gcnt,
                                               const int* __restrict__ partBuf,
                                               int* __restrict__ cnt,
                                               ushortT* __restrict__ adj,
                                               float* __restrict__ dinv,
                                               __hip_bfloat16* __restrict__ h1b) {
    __shared__ int scnt[PART_BLOCKS];
    __shared__ int pre[PART_BLOCKS + 1];
    __shared__ int dense[CAP];
    __shared__ int ldeg[NPB];
    __shared__ int cur[NPB];
    __shared__ float sdv[NPB];
    int t = threadIdx.x;
    int b = blockIdx.x;                 // 0..249
    int nodeBase = b * NPB;
    if (t < PART_BLOCKS) scnt[t] = gcnt[t * NB + b];
    if (t < NPB) ldeg[t] = 0;
    __syncthreads();
    if (t < PART_BLOCKS) pre[t + 1] = scnt[t];
    if (t == 0) pre[0] = 0;
    __syncthreads();
    for (int off = 1; off < PART_BLOCKS; off <<= 1) {
        int v = 0;
        if (t >= off && t < PART_BLOCKS) v = pre[t + 1 - off];
        __syncthreads();
        if (t >= off && t < PART_BLOCKS) pre[t + 1] += v;
        __syncthreads();
    }
    int tot = pre[PART_BLOCKS]; if (tot > CAP) tot = CAP;
    if (t < PART_BLOCKS) {
        int c = scnt[t], base = pre[t];
        const int* rp = partBuf + (b * PART_BLOCKS + t) * STAGE_C;
        for (int k = 0; k < c; ++k) {
            int dd = base + k;
            if (dd < CAP) dense[dd] = rp[k];
        }
    }
    __syncthreads();
    for (int i = t; i < tot; i += 512)
        atomicAdd(&ldeg[dense[i] >> 14], 1);
    __syncthreads();
    if (t < NPB) {
        int v = nodeBase + t;
        int c = ldeg[t];
        cnt[v] = c;
        float dv_ = rsqrtf((float)c + 1.0f);
        dinv[v] = dv_;
        sdv[t] = dv_;
        cur[t] = 0;
    }
    __syncthreads();
    for (int i = t; i < tot; i += 512) {
        int p = dense[i];
        int ln = p >> 14;
        int pos = atomicAdd(&cur[ln], 1);
        if (pos < MAXDEG) adj[(nodeBase + ln) * MAXDEG + pos] = (ushortT)(p & 16383);
    }
    unsigned* h1u = (unsigned*)h1b;
    for (int i = t; i < NPB * 32; i += 512) {
        int ln = i >> 5, pp = i & 31;
        int v = nodeBase + ln;
        unsigned u = h1u[v * 32 + pp];
        float d = sdv[ln];
        h1u[v * 32 + pp] = bf_pack(bf_lo(u) * d, bf_hi(u) * d);
    }
}

// ---------- dispatch 3: gather layer1 (u64 lanes: 4 feats/lane) + ReLU + GEMM2 ----------
// 625 blocks x 256 threads = 16 nodes x 16 lanes; lane owns 4 features (8B loads
// halve wave-instruction count vs the 4B/lane version).
__global__ void __launch_bounds__(256) k_gather1_gemm2(const __hip_bfloat16* __restrict__ h1b,
                                const int* __restrict__ cnt,
                                const ushortT* __restrict__ adj,
                                const float* __restrict__ dinv,
                                const float* __restrict__ b1,
                                const float* __restrict__ W2,
                                __hip_bfloat16* __restrict__ h2b) {
    __shared__ float h1s[16 * 68];          // stride 68: kills 4-way bank conflict in GEMM2
    __shared__ ushortT idxs[16 * MAXDEG];   // 4 KB
    __shared__ float w2s[H1 * H2];          // 8 KB
    int t = threadIdx.x;
    int n = t >> 4;         // node slot 0..15
    int l = t & 15;         // lane: features 4l..4l+3
    int v0 = blockIdx.x * 16;
    int v = v0 + n;         // 625*16 = 10000 exact
    const float4* W24 = (const float4*)W2;
    float4* w2s4 = (float4*)w2s;
#pragma unroll
    for (int i = 0; i < 2; ++i) w2s4[i * 256 + t] = W24[i * 256 + t];
    // stage 16 adj rows (16*128 u16 = 1024 u32), contiguous
    const unsigned* a32 = (const unsigned*)(adj + (long)v0 * MAXDEG);
    unsigned* i32 = (unsigned*)idxs;
#pragma unroll
    for (int i = 0; i < 4; ++i) i32[i * 256 + t] = a32[i * 256 + t];
    int deg = cnt[v]; if (deg > MAXDEG) deg = MAXDEG;
    float dv_ = dinv[v];
    const u64T* h164 = (const u64T*)h1b;    // row = 16 u64
    u64T su = h164[v * 16 + l];             // self-loop (pre-scaled by dinv[v])
    unsigned slo = (unsigned)su, shi = (unsigned)(su >> 32);
    float f0 = bf_lo(slo), f1 = bf_hi(slo), f2 = bf_lo(shi), f3 = bf_hi(shi);
    float p0 = 0.f, p1 = 0.f, p2 = 0.f, p3 = 0.f;
    float q0 = 0.f, q1 = 0.f, q2 = 0.f, q3 = 0.f;
    __syncthreads();
    const ushortT* myRow = &idxs[n * MAXDEG];
    int e = 0;
    for (; e + 8 <= deg; e += 8) {          // 8 x 8B loads in flight
        int i0 = myRow[e],     i1 = myRow[e + 1];
        int i2 = myRow[e + 2], i3 = myRow[e + 3];
        int i4 = myRow[e + 4], i5 = myRow[e + 5];
        int i6 = myRow[e + 6], i7 = myRow[e + 7];
        u64T u0 = h164[i0 * 16 + l];
        u64T u1 = h164[i1 * 16 + l];
        u64T u2 = h164[i2 * 16 + l];
        u64T u3 = h164[i3 * 16 + l];
        u64T u4 = h164[i4 * 16 + l];
        u64T u5 = h164[i5 * 16 + l];
        u64T u6 = h164[i6 * 16 + l];
        u64T u7 = h164[i7 * 16 + l];
        unsigned lo, hi;
        lo = (unsigned)u0; hi = (unsigned)(u0 >> 32);
        p0 += bf_lo(lo); p1 += bf_hi(lo); p2 += bf_lo(hi); p3 += bf_hi(hi);
        lo = (unsigned)u1; hi = (unsigned)(u1 >> 32);
        q0 += bf_lo(lo); q1 += bf_hi(lo); q2 += bf_lo(hi); q3 += bf_hi(hi);
        lo = (unsigned)u2; hi = (unsigned)(u2 >> 32);
        p0 += bf_lo(lo); p1 += bf_hi(lo); p2 += bf_lo(hi); p3 += bf_hi(hi);
        lo = (unsigned)u3; hi = (unsigned)(u3 >> 32);
        q0 += bf_lo(lo); q1 += bf_hi(lo); q2 += bf_lo(hi); q3 += bf_hi(hi);
        lo = (unsigned)u4; hi = (unsigned)(u4 >> 32);
        p0 += bf_lo(lo); p1 += bf_hi(lo); p2 += bf_lo(hi); p3 += bf_hi(hi);
        lo = (unsigned)u5; hi = (unsigned)(u5 >> 32);
        q0 += bf_lo(lo); q1 += bf_hi(lo); q2 += bf_lo(hi); q3 += bf_hi(hi);
        lo = (unsigned)u6; hi = (unsigned)(u6 >> 32);
        p0 += bf_lo(lo); p1 += bf_hi(lo); p2 += bf_lo(hi); p3 += bf_hi(hi);
        lo = (unsigned)u7; hi = (unsigned)(u7 >> 32);
        q0 += bf_lo(lo); q1 += bf_hi(lo); q2 += bf_lo(hi); q3 += bf_hi(hi);
    }
    for (; e < deg; ++e) {
        u64T u = h164[myRow[e] * 16 + l];
        unsigned lo = (unsigned)u, hi = (unsigned)(u >> 32);
        p0 += bf_lo(lo); p1 += bf_hi(lo); p2 += bf_lo(hi); p3 += bf_hi(hi);
    }
    f0 += p0 + q0; f1 += p1 + q1; f2 += p2 + q2; f3 += p3 + q3;
    float4 bb = ((const float4*)b1)[l];
    float4 r;
    r.x = fmaxf(dv_ * f0 + bb.x, 0.f);
    r.y = fmaxf(dv_ * f1 + bb.y, 0.f);
    r.z = fmaxf(dv_ * f2 + bb.z, 0.f);
    r.w = fmaxf(dv_ * f3 + bb.w, 0.f);
    ((float4*)(h1s + n * 68))[l] = r;
    __syncthreads();
    // GEMM2: thread = (node n, output pair j=2l,2l+1)
    float acc0 = 0.f, acc1 = 0.f;
#pragma unroll
    for (int kk = 0; kk < H1; ++kk) {
        float hv = h1s[n * 68 + kk];
        float2 w = ((const float2*)(w2s + kk * H2))[l];
        acc0 += hv * w.x;
        acc1 += hv * w.y;
    }
    ((unsigned*)h2b)[v * 16 + l] = bf_pack(acc0 * dv_, acc1 * dv_);  // pre-scaled
}

// ---------- dispatch 4: gather layer2 (u64 lanes) + ReLU + mean + FC -> out ----------
// 313 blocks x 256 threads = 32 nodes x 8 lanes; lane owns 4 features of H2.
__global__ void __launch_bounds__(256) k_gather2_out(const __hip_bfloat16* __restrict__ h2b,
                               const int* __restrict__ cnt,
                               const ushortT* __restrict__ adj,
                               const float* __restrict__ dinv,
                               const float* __restrict__ b2,
                               const float* __restrict__ Wfc,
                               float* __restrict__ out) {
    __shared__ float red[32 * 36];           // stride 36 (pad)
    __shared__ ushortT idxs[32 * MAXDEG];    // 8 KB
    __shared__ float gs[H2];
    int t = threadIdx.x;
    int n = t >> 3;         // node slot 0..31
    int l = t & 7;          // lane: features 4l..4l+3 of H2
    int v0 = blockIdx.x * 32;
    int v = v0 + n;         // 313*32 = 10016 >= 10000
    bool valid = v < N_NODES;
    const unsigned* a32 = (const unsigned*)(adj + (long)v0 * MAXDEG);
    unsigned* i32 = (unsigned*)idxs;
#pragma unroll
    for (int i = 0; i < 8; ++i) i32[i * 256 + t] = a32[i * 256 + t];
    int deg = valid ? cnt[v] : 0; if (deg > MAXDEG) deg = MAXDEG; if (deg < 0) deg = 0;
    float dv_ = valid ? dinv[v] : 0.f;
    const u64T* h264 = (const u64T*)h2b;     // row = 8 u64
    u64T su = valid ? h264[v * 8 + l] : 0ull;  // self-loop (pre-scaled)
    unsigned slo = (unsigned)su, shi = (unsigned)(su >> 32);
    float f0 = bf_lo(slo), f1 = bf_hi(slo), f2 = bf_lo(shi), f3 = bf_hi(shi);
    float p0 = 0.f, p1 = 0.f, p2 = 0.f, p3 = 0.f;
    float q0 = 0.f, q1 = 0.f, q2 = 0.f, q3 = 0.f;
    __syncthreads();
    const ushortT* myRow = &idxs[n * MAXDEG];
    int e = 0;
    for (; e + 8 <= deg; e += 8) {
        int i0 = myRow[e],     i1 = myRow[e + 1];
        int i2 = myRow[e + 2], i3 = myRow[e + 3];
        int i4 = myRow[e + 4], i5 = myRow[e + 5];
        int i6 = myRow[e + 6], i7 = myRow[e + 7];
        u64T u0 = h264[i0 * 8 + l];
        u64T u1 = h264[i1 * 8 + l];
        u64T u2 = h264[i2 * 8 + l];
        u64T u3 = h264[i3 * 8 + l];
        u64T u4 = h264[i4 * 8 + l];
        u64T u5 = h264[i5 * 8 + l];
        u64T u6 = h264[i6 * 8 + l];
        u64T u7 = h264[i7 * 8 + l];
        unsigned lo, hi;
        lo = (unsigned)u0; hi = (unsigned)(u0 >> 32);
        p0 += bf_lo(lo); p1 += bf_hi(lo); p2 += bf_lo(hi); p3 += bf_hi(hi);
        lo = (unsigned)u1; hi = (unsigned)(u1 >> 32);
        q0 += bf_lo(lo); q1 += bf_hi(lo); q2 += bf_lo(hi); q3 += bf_hi(hi);
        lo = (unsigned)u2; hi = (unsigned)(u2 >> 32);
        p0 += bf_lo(lo); p1 += bf_hi(lo); p2 += bf_lo(hi); p3 += bf_hi(hi);
        lo = (unsigned)u3; hi = (unsigned)(u3 >> 32);
        q0 += bf_lo(lo); q1 += bf_hi(lo); q2 += bf_lo(hi); q3 += bf_hi(hi);
        lo = (unsigned)u4; hi = (unsigned)(u4 >> 32);
        p0 += bf_lo(lo); p1 += bf_hi(lo); p2 += bf_lo(hi); p3 += bf_hi(hi);
        lo = (unsigned)u5; hi = (unsigned)(u5 >> 32);
        q0 += bf_lo(lo); q1 += bf_hi(lo); q2 += bf_lo(hi); q3 += bf_hi(hi);
        lo = (unsigned)u6; hi = (unsigned)(u6 >> 32);
        p0 += bf_lo(lo); p1 += bf_hi(lo); p2 += bf_lo(hi); p3 += bf_hi(hi);
        lo = (unsigned)u7; hi = (unsigned)(u7 >> 32);
        q0 += bf_lo(lo); q1 += bf_hi(lo); q2 += bf_lo(hi); q3 += bf_hi(hi);
    }
    for (; e < deg; ++e) {
        u64T u = h264[myRow[e] * 8 + l];
        unsigned lo = (unsigned)u, hi = (unsigned)(u >> 32);
        p0 += bf_lo(lo); p1 += bf_hi(lo); p2 += bf_lo(hi); p3 += bf_hi(hi);
    }
    f0 += p0 + q0; f1 += p1 + q1; f2 += p2 + q2; f3 += p3 + q3;
    float4 bb = ((const float4*)b2)[l];
    float4 r;
    r.x = fmaxf(dv_ * f0 + bb.x, 0.f);
    r.y = fmaxf(dv_ * f1 + bb.y, 0.f);
    r.z = fmaxf(dv_ * f2 + bb.z, 0.f);
    r.w = fmaxf(dv_ * f3 + bb.w, 0.f);
    if (!valid) { r.x = 0.f; r.y = 0.f; r.z = 0.f; r.w = 0.f; }
    ((float4*)(red + n * 36))[l] = r;
    __syncthreads();
    if (t < H2) {
        float s = 0.f;
#pragma unroll
        for (int rr = 0; rr < 32; ++rr) s += red[rr * 36 + t];
        gs[t] = s;
    }
    __syncthreads();
    if (t < N_CLASSES) {
        float acc = 0.f;
#pragma unroll
        for (int j = 0; j < H2; ++j)
            acc += gs[j] * Wfc[j * N_CLASSES + t];
        atomicAdd(&out[t], acc * (1.0f / (float)N_NODES));
    }
}

extern "C" void kernel_launch(void* const* d_in, const int* in_sizes, int n_in,
                              void* d_out, int out_size, void* d_ws, size_t ws_size,
                              hipStream_t stream) {
    const float* x   = (const float*)d_in[0];
    const float* W1  = (const float*)d_in[1];
    const float* b1  = (const float*)d_in[2];
    const float* W2  = (const float*)d_in[3];
    const float* b2  = (const float*)d_in[4];
    const float* Wfc = (const float*)d_in[5];
    const float* bfc = (const float*)d_in[6];
    const int* edge  = (const int*)d_in[7];
    const int* srcI = edge;              // edge_index[0]
    const int* dstI = edge + N_EDGES;    // edge_index[1]
    float* out = (float*)d_out;

    // workspace layout (~15.2 MB). NO init required anywhere.
    // adj padded to 10016 rows (gather2's last block stages rows 9984..10015).
    char* ws = (char*)d_ws;
    int*     gcnt    = (int*)    (ws + 0);         // 313*256 ints = 320512 B
    int*     cnt     = (int*)    (ws + 321536);    // 10000 ints
    float*   dinv    = (float*)  (ws + 362496);    // 10000 f
    int*     partBuf = (int*)    (ws + 403456);    // 256*313*32 ints = 10256384 B
    ushortT* adj     = (ushortT*)(ws + 10659840);  // 10016*128 u16 = 2564096 B
    __hip_bfloat16* h1b = (__hip_bfloat16*)(ws + 13223936);  // 640000 bf16
    __hip_bfloat16* h2b = (__hip_bfloat16*)(ws + 14503936);  // 320000 bf16 -> 15143936

    k_part_gemm1<<<PART_BLOCKS + GEMM_TILES, 256, 0, stream>>>(
        srcI, dstI, gcnt, partBuf, x, W1, h1b, bfc, out);
    k_place<<<250, 512, 0, stream>>>(gcnt, partBuf, cnt, adj, dinv, h1b);
    k_gather1_gemm2<<<625, 256, 0, stream>>>(h1b, cnt, adj, dinv, b1, W2, h2b);
    k_gather2_out<<<313, 256, 0, stream>>>(h2b, cnt, adj, dinv, b2, Wfc, out);
}